// Round 1
// baseline (1270.403 us; speedup 1.0000x reference)
//
#include <hip/hip_runtime.h>
#include <math.h>

#define THREADS 256

// ---------------- CSR build ----------------
__global__ void hist_k(const int* __restrict__ dstv, int* __restrict__ counts, int E) {
  int i = blockIdx.x * THREADS + threadIdx.x;
  if (i < E) atomicAdd(&counts[dstv[i]], 1);
}

__global__ void scan1_k(const int* __restrict__ counts, int* __restrict__ offs,
                        int* __restrict__ bsums, int N) {
  __shared__ int s[THREADS];
  int i = blockIdx.x * THREADS + threadIdx.x;
  int v = (i < N) ? counts[i] : 0;
  s[threadIdx.x] = v;
  __syncthreads();
  for (int off = 1; off < THREADS; off <<= 1) {
    int t = (threadIdx.x >= off) ? s[threadIdx.x - off] : 0;
    __syncthreads();
    s[threadIdx.x] += t;
    __syncthreads();
  }
  if (i < N) offs[i] = s[threadIdx.x] - v;  // exclusive within block
  if (threadIdx.x == THREADS - 1) bsums[blockIdx.x] = s[THREADS - 1];
}

__global__ void scan2_k(int* bsums, int nb) {
  if (blockIdx.x == 0 && threadIdx.x == 0) {
    int run = 0;
    for (int b = 0; b < nb; b++) { int t = bsums[b]; bsums[b] = run; run += t; }
  }
}

__global__ void scan3_k(int* offs, const int* __restrict__ bsums, int N, int E) {
  int i = blockIdx.x * THREADS + threadIdx.x;
  if (i < N) offs[i] += bsums[blockIdx.x];
  if (i == 0) offs[N] = E;
}

__global__ void scatter_k(const int* __restrict__ srcv, const int* __restrict__ dstv,
                          const int* __restrict__ offs, int* __restrict__ cursor,
                          int* __restrict__ csr, int E) {
  int i = blockIdx.x * THREADS + threadIdx.x;
  if (i < E) {
    int d = dstv[i];
    int p = offs[d] + atomicAdd(&cursor[d], 1);
    csr[p] = srcv[i];
  }
}

// ---------------- GAT node transform: h = act(x) @ W, plus attention dots ----------------
// One wave per node; lane = output channel (64). If PRE, input is pre-BN and we
// apply scale/shift (ssc[0..63]=scale, ssc[64..127]=shift) + ELU first.
template <int K, bool PRE>
__global__ void gat_transform(const float* __restrict__ xin, const float* __restrict__ ssc,
                              const float* __restrict__ W, const float* __restrict__ aS,
                              const float* __restrict__ aD, float* __restrict__ h,
                              float* __restrict__ als, float* __restrict__ ald,
                              int N, int H) {
  int wave = threadIdx.x >> 6;
  int lane = threadIdx.x & 63;
  int n = blockIdx.x * 4 + wave;
  __shared__ float xs[4][K];
  if (n < N && lane < K) {
    float v = xin[(long long)n * K + lane];
    if (PRE) {
      v = v * ssc[lane] + ssc[64 + lane];
      v = v > 0.f ? v : (expf(v) - 1.f);  // ELU
    }
    xs[wave][lane] = v;
  }
  __syncthreads();
  if (n >= N) return;
  float acc = 0.f;
#pragma unroll
  for (int k = 0; k < K; k++) acc += xs[wave][k] * W[k * 64 + lane];
  h[(long long)n * 64 + lane] = acc;
  int C = 64 / H;
  float ts = acc * aS[lane], td = acc * aD[lane];
  for (int m = 1; m < C; m <<= 1) {
    ts += __shfl_xor(ts, m, 64);
    td += __shfl_xor(td, m, 64);
  }
  if ((lane & (C - 1)) == 0) {
    int hh = lane / C;
    als[(long long)n * H + hh] = ts;
    ald[(long long)n * H + hh] = td;
  }
}

// ---------------- Fused attention gather (online softmax), wave per node ----------------
__global__ void gat_gather(const float* __restrict__ h, const float* __restrict__ als,
                           const float* __restrict__ ald, const int* __restrict__ offs,
                           const int* __restrict__ csr, const float* __restrict__ bias,
                           float* __restrict__ pre, int N, int H) {
  int wave = threadIdx.x >> 6, lane = threadIdx.x & 63;
  int n = blockIdx.x * 4 + wave;
  if (n >= N) return;
  int C = 64 / H;
  int hh = lane / C;
  float aldn = ald[(long long)n * H + hh];
  // self-loop first
  float m = als[(long long)n * H + hh] + aldn;
  m = m >= 0.f ? m : 0.2f * m;  // leaky_relu(0.2)
  float s = 1.f;
  float acc = h[(long long)n * 64 + lane];
  int e0 = offs[n], e1 = offs[n + 1];
  for (int e = e0; e < e1; e++) {
    int sn = csr[e];
    float ev = als[(long long)sn * H + hh] + aldn;
    ev = ev >= 0.f ? ev : 0.2f * ev;
    float mn = fmaxf(m, ev);
    float r = expf(m - mn);
    float p = expf(ev - mn);
    s = s * r + p;
    acc = acc * r + h[(long long)sn * 64 + lane] * p;
    m = mn;
  }
  pre[(long long)n * 64 + lane] = acc / (s + 1e-16f) + bias[lane];
}

// ---------------- BatchNorm statistics ----------------
__global__ void bn_stats(const float* __restrict__ x, float* __restrict__ stats, int N) {
  int tid = threadIdx.x;
  int f = tid & 63;
  long long total = (long long)N * 64;
  long long stride = (long long)gridDim.x * THREADS;
  float s = 0.f, q = 0.f;
  for (long long i = (long long)blockIdx.x * THREADS + tid; i < total; i += stride) {
    float v = x[i];
    s += v;
    q += v * v;
  }
  __shared__ float ls[THREADS], lq[THREADS];
  ls[tid] = s;
  lq[tid] = q;
  __syncthreads();
  if (tid < 64) {
    s = ls[tid] + ls[tid + 64] + ls[tid + 128] + ls[tid + 192];
    q = lq[tid] + lq[tid + 64] + lq[tid + 128] + lq[tid + 192];
    atomicAdd(&stats[f], s);
    atomicAdd(&stats[64 + f], q);
  }
}

__global__ void bn_finalize(const float* __restrict__ stats, const float* __restrict__ g,
                            const float* __restrict__ be, float* __restrict__ ssc, int N) {
  int f = threadIdx.x;  // 64 threads
  float inv = 1.f / (float)N;
  float mu = stats[f] * inv;
  float var = stats[64 + f] * inv - mu * mu;
  float rstd = rsqrtf(var + 1e-5f);
  float sc = rstd * g[f];
  ssc[f] = sc;
  ssc[64 + f] = be[f] - mu * sc;
}

// ---------------- node embeddings = elu(bn(pre3)) ----------------
__global__ void node_emb_k(const float* __restrict__ pre, const float* __restrict__ ssc,
                           float* __restrict__ out, int N) {
  long long i = (long long)blockIdx.x * THREADS + threadIdx.x;
  long long total = (long long)N * 64;
  if (i >= total) return;
  int f = (int)(i & 63);
  float v = pre[i] * ssc[f] + ssc[64 + f];
  out[i] = v > 0.f ? v : (expf(v) - 1.f);
}

// ---------------- global mean pool, one block per graph (batch is sorted) ----------------
__global__ void pool_k(const float* __restrict__ nemb, const int* __restrict__ batch,
                       float* __restrict__ pool, int N) {
  int g = blockIdx.x, lane = threadIdx.x;
  __shared__ int bnds[2];
  if (lane < 2) {
    int target = g + lane;  // lower_bound(batch, target)
    int lo = 0, hi = N;
    while (lo < hi) {
      int mid = (lo + hi) >> 1;
      if (batch[mid] < target) lo = mid + 1; else hi = mid;
    }
    bnds[lane] = lo;
  }
  __syncthreads();
  int lo = bnds[0], hi = bnds[1];
  float acc = 0.f;
  for (int n = lo; n < hi; n++) acc += nemb[(long long)n * 64 + lane];
  float cnt = (float)(hi - lo);
  pool[g * 64 + lane] = acc / fmaxf(cnt, 1.f);
}

// ---------------- classifier + embedding head, one block per graph ----------------
__global__ void head_k(const float* __restrict__ pool, const float* __restrict__ Wc1,
                       const float* __restrict__ bc1, const float* __restrict__ Wc2,
                       const float* __restrict__ bc2, const float* __restrict__ We,
                       const float* __restrict__ bee, float* __restrict__ logits,
                       float* __restrict__ emb) {
  int g = blockIdx.x, lane = threadIdx.x;  // 64 threads
  __shared__ float pr[64], hid[32];
  pr[lane] = pool[g * 64 + lane];
  __syncthreads();
  if (lane < 32) {
    float a = bc1[lane];
    for (int k = 0; k < 64; k++) a += pr[k] * Wc1[k * 32 + lane];
    hid[lane] = fmaxf(a, 0.f);
  }
  float e = bee[lane];
  for (int k = 0; k < 64; k++) e += pr[k] * We[k * 64 + lane];
  emb[g * 64 + lane] = e;
  __syncthreads();
  if (lane < 2) {
    float l = bc2[lane];
    for (int k = 0; k < 32; k++) l += hid[k] * Wc2[k * 2 + lane];
    logits[g * 2 + lane] = l;
  }
}

extern "C" void kernel_launch(void* const* d_in, const int* in_sizes, int n_in,
                              void* d_out, int out_size, void* d_ws, size_t ws_size,
                              hipStream_t stream) {
  const float* x    = (const float*)d_in[0];
  const int*   ei   = (const int*)d_in[1];
  const int*   batch= (const int*)d_in[2];
  const float* W1   = (const float*)d_in[3];
  const float* as1  = (const float*)d_in[4];
  const float* ad1  = (const float*)d_in[5];
  const float* b1   = (const float*)d_in[6];
  const float* g1   = (const float*)d_in[7];
  const float* be1  = (const float*)d_in[8];
  const float* W2   = (const float*)d_in[9];
  const float* as2  = (const float*)d_in[10];
  const float* ad2  = (const float*)d_in[11];
  const float* b2   = (const float*)d_in[12];
  const float* g2   = (const float*)d_in[13];
  const float* be2  = (const float*)d_in[14];
  const float* W3   = (const float*)d_in[15];
  const float* as3  = (const float*)d_in[16];
  const float* ad3  = (const float*)d_in[17];
  const float* b3   = (const float*)d_in[18];
  const float* g3   = (const float*)d_in[19];
  const float* be3  = (const float*)d_in[20];
  const float* Wc1  = (const float*)d_in[21];
  const float* bc1  = (const float*)d_in[22];
  const float* Wc2  = (const float*)d_in[23];
  const float* bc2  = (const float*)d_in[24];
  const float* We   = (const float*)d_in[25];
  const float* bee  = (const float*)d_in[26];

  int N = in_sizes[0] / 12;
  int E = in_sizes[1] / 2;
  const int* srcv = ei;
  const int* dstv = ei + E;

  char* p = (char*)d_ws;
  auto carve = [&](size_t bytes) -> char* {
    char* r = p;
    p += (bytes + 255) & ~(size_t)255;
    return r;
  };
  int* counts  = (int*)carve((size_t)N * 4);
  int* cursor  = (int*)carve((size_t)N * 4);
  int* offs    = (int*)carve((size_t)(N + 1) * 4);
  int* bsums   = (int*)carve(4096 * 4);
  int* csr     = (int*)carve((size_t)E * 4);
  float* h     = (float*)carve((size_t)N * 64 * 4);
  float* als   = (float*)carve((size_t)N * 4 * 4);
  float* ald   = (float*)carve((size_t)N * 4 * 4);
  float* preA  = (float*)carve((size_t)N * 64 * 4);
  float* preB  = (float*)carve((size_t)N * 64 * 4);
  float* statsAll = (float*)carve(3 * 128 * 4);
  float* sscAll   = (float*)carve(3 * 128 * 4);
  float* poolbuf  = (float*)carve(64 * 64 * 4);

  hipMemsetAsync(counts, 0, (size_t)N * 4, stream);
  hipMemsetAsync(cursor, 0, (size_t)N * 4, stream);
  hipMemsetAsync(statsAll, 0, 3 * 128 * 4, stream);

  int nbE = (E + THREADS - 1) / THREADS;
  int nbN = (N + THREADS - 1) / THREADS;
  hist_k<<<nbE, THREADS, 0, stream>>>(dstv, counts, E);
  scan1_k<<<nbN, THREADS, 0, stream>>>(counts, offs, bsums, N);
  scan2_k<<<1, 64, 0, stream>>>(bsums, nbN);
  scan3_k<<<nbN, THREADS, 0, stream>>>(offs, bsums, N, E);
  scatter_k<<<nbE, THREADS, 0, stream>>>(srcv, dstv, offs, cursor, csr, E);

  int nbNode = (N + 3) / 4;
  // ---- layer 1 (K=12, H=4) ----
  gat_transform<12, false><<<nbNode, THREADS, 0, stream>>>(x, nullptr, W1, as1, ad1, h, als, ald, N, 4);
  gat_gather<<<nbNode, THREADS, 0, stream>>>(h, als, ald, offs, csr, b1, preA, N, 4);
  bn_stats<<<1024, THREADS, 0, stream>>>(preA, statsAll + 0, N);
  bn_finalize<<<1, 64, 0, stream>>>(statsAll + 0, g1, be1, sscAll + 0, N);
  // ---- layer 2 (K=64, H=4) ----
  gat_transform<64, true><<<nbNode, THREADS, 0, stream>>>(preA, sscAll + 0, W2, as2, ad2, h, als, ald, N, 4);
  gat_gather<<<nbNode, THREADS, 0, stream>>>(h, als, ald, offs, csr, b2, preB, N, 4);
  bn_stats<<<1024, THREADS, 0, stream>>>(preB, statsAll + 128, N);
  bn_finalize<<<1, 64, 0, stream>>>(statsAll + 128, g2, be2, sscAll + 128, N);
  // ---- layer 3 (K=64, H=1) ----
  gat_transform<64, true><<<nbNode, THREADS, 0, stream>>>(preB, sscAll + 128, W3, as3, ad3, h, als, ald, N, 1);
  gat_gather<<<nbNode, THREADS, 0, stream>>>(h, als, ald, offs, csr, b3, preA, N, 1);
  bn_stats<<<1024, THREADS, 0, stream>>>(preA, statsAll + 256, N);
  bn_finalize<<<1, 64, 0, stream>>>(statsAll + 256, g3, be3, sscAll + 256, N);

  float* outF   = (float*)d_out;
  float* logits = outF;
  float* emb    = outF + 64 * 2;
  float* nemb   = outF + 64 * 2 + 64 * 64;
  long long tot = (long long)N * 64;
  node_emb_k<<<(int)((tot + THREADS - 1) / THREADS), THREADS, 0, stream>>>(preA, sscAll + 256, nemb, N);
  pool_k<<<64, 64, 0, stream>>>(nemb, batch, poolbuf, N);
  head_k<<<64, 64, 0, stream>>>(poolbuf, Wc1, bc1, Wc2, bc2, We, bee, logits, emb);
}

// Round 2
// 914.724 us; speedup vs baseline: 1.3888x; 1.3888x over previous
//
#include <hip/hip_runtime.h>
#include <math.h>

#define THREADS 256

// ---------------- CSR build ----------------
__global__ void hist_k(const int* __restrict__ dstv, int* __restrict__ counts, int E) {
  int i = blockIdx.x * THREADS + threadIdx.x;
  if (i < E) atomicAdd(&counts[dstv[i]], 1);
}

__global__ void scan1_k(const int* __restrict__ counts, int* __restrict__ offs,
                        int* __restrict__ bsums, int N) {
  __shared__ int s[THREADS];
  int i = blockIdx.x * THREADS + threadIdx.x;
  int v = (i < N) ? counts[i] : 0;
  s[threadIdx.x] = v;
  __syncthreads();
  for (int off = 1; off < THREADS; off <<= 1) {
    int t = (threadIdx.x >= off) ? s[threadIdx.x - off] : 0;
    __syncthreads();
    s[threadIdx.x] += t;
    __syncthreads();
  }
  if (i < N) offs[i] = s[threadIdx.x] - v;  // exclusive within block
  if (threadIdx.x == THREADS - 1) bsums[blockIdx.x] = s[THREADS - 1];
}

__global__ void scan2_k(int* bsums, int nb) {
  if (blockIdx.x == 0 && threadIdx.x == 0) {
    int run = 0;
    for (int b = 0; b < nb; b++) { int t = bsums[b]; bsums[b] = run; run += t; }
  }
}

__global__ void scan3_k(int* offs, const int* __restrict__ bsums, int N, int E) {
  int i = blockIdx.x * THREADS + threadIdx.x;
  if (i < N) offs[i] += bsums[blockIdx.x];
  if (i == 0) offs[N] = E;
}

__global__ void scatter_k(const int* __restrict__ srcv, const int* __restrict__ dstv,
                          const int* __restrict__ offs, int* __restrict__ cursor,
                          int* __restrict__ csr, int E) {
  int i = blockIdx.x * THREADS + threadIdx.x;
  if (i < E) {
    int d = dstv[i];
    int p = offs[d] + atomicAdd(&cursor[d], 1);
    csr[p] = srcv[i];
  }
}

// ---------------- GAT node transform: h = act(x) @ W, plus attention dots ----------------
template <int K, bool PRE>
__global__ void gat_transform(const float* __restrict__ xin, const float* __restrict__ ssc,
                              const float* __restrict__ W, const float* __restrict__ aS,
                              const float* __restrict__ aD, float* __restrict__ h,
                              float* __restrict__ als, float* __restrict__ ald,
                              int N, int H) {
  int wave = threadIdx.x >> 6;
  int lane = threadIdx.x & 63;
  int n = blockIdx.x * 4 + wave;
  __shared__ float xs[4][K];
  if (n < N && lane < K) {
    float v = xin[(long long)n * K + lane];
    if (PRE) {
      v = v * ssc[lane] + ssc[64 + lane];
      v = v > 0.f ? v : (expf(v) - 1.f);  // ELU
    }
    xs[wave][lane] = v;
  }
  __syncthreads();
  if (n >= N) return;
  float acc = 0.f;
#pragma unroll
  for (int k = 0; k < K; k++) acc += xs[wave][k] * W[k * 64 + lane];
  h[(long long)n * 64 + lane] = acc;
  int C = 64 / H;
  float ts = acc * aS[lane], td = acc * aD[lane];
  for (int m = 1; m < C; m <<= 1) {
    ts += __shfl_xor(ts, m, 64);
    td += __shfl_xor(td, m, 64);
  }
  if ((lane & (C - 1)) == 0) {
    int hh = lane / C;
    als[(long long)n * H + hh] = ts;
    ald[(long long)n * H + hh] = td;
  }
}

// ---------------- Fused attention gather (online softmax), wave per node ----------------
__global__ void gat_gather(const float* __restrict__ h, const float* __restrict__ als,
                           const float* __restrict__ ald, const int* __restrict__ offs,
                           const int* __restrict__ csr, const float* __restrict__ bias,
                           float* __restrict__ pre, int N, int H) {
  int wave = threadIdx.x >> 6, lane = threadIdx.x & 63;
  int n = blockIdx.x * 4 + wave;
  if (n >= N) return;
  int C = 64 / H;
  int hh = lane / C;
  float aldn = ald[(long long)n * H + hh];
  // self-loop first
  float m = als[(long long)n * H + hh] + aldn;
  m = m >= 0.f ? m : 0.2f * m;  // leaky_relu(0.2)
  float s = 1.f;
  float acc = h[(long long)n * 64 + lane];
  int e0 = offs[n], e1 = offs[n + 1];
  for (int e = e0; e < e1; e++) {
    int sn = csr[e];
    float ev = als[(long long)sn * H + hh] + aldn;
    ev = ev >= 0.f ? ev : 0.2f * ev;
    float mn = fmaxf(m, ev);
    float r = expf(m - mn);
    float p = expf(ev - mn);
    s = s * r + p;
    acc = acc * r + h[(long long)sn * 64 + lane] * p;
    m = mn;
  }
  pre[(long long)n * 64 + lane] = acc / (s + 1e-16f) + bias[lane];
}

// ---------------- BatchNorm statistics ----------------
__global__ void bn_stats(const float* __restrict__ x, float* __restrict__ stats, int N) {
  int tid = threadIdx.x;
  int f = tid & 63;
  long long total = (long long)N * 64;
  long long stride = (long long)gridDim.x * THREADS;
  float s = 0.f, q = 0.f;
  for (long long i = (long long)blockIdx.x * THREADS + tid; i < total; i += stride) {
    float v = x[i];
    s += v;
    q += v * v;
  }
  __shared__ float ls[THREADS], lq[THREADS];
  ls[tid] = s;
  lq[tid] = q;
  __syncthreads();
  if (tid < 64) {
    s = ls[tid] + ls[tid + 64] + ls[tid + 128] + ls[tid + 192];
    q = lq[tid] + lq[tid + 64] + lq[tid + 128] + lq[tid + 192];
    atomicAdd(&stats[f], s);
    atomicAdd(&stats[64 + f], q);
  }
}

__global__ void bn_finalize(const float* __restrict__ stats, const float* __restrict__ g,
                            const float* __restrict__ be, float* __restrict__ ssc, int N) {
  int f = threadIdx.x;  // 64 threads
  float inv = 1.f / (float)N;
  float mu = stats[f] * inv;
  float var = stats[64 + f] * inv - mu * mu;
  float rstd = rsqrtf(var + 1e-5f);
  float sc = rstd * g[f];
  ssc[f] = sc;
  ssc[64 + f] = be[f] - mu * sc;
}

// ---------------- fused: nemb = elu(bn(pre3)); pool partial sums via per-wave run ----------------
// One wave per contiguous node chunk; lane = channel. batch sorted -> few flushes.
__global__ void emb_pool_k(const float* __restrict__ pre, const float* __restrict__ ssc,
                           const int* __restrict__ batch, float* __restrict__ nemb,
                           float* __restrict__ pool, int N, int per) {
  int lane = threadIdx.x & 63, wid = threadIdx.x >> 6;
  int gw = blockIdx.x * 4 + wid;
  int n0 = gw * per;
  int n1 = n0 + per; if (n1 > N) n1 = N;
  if (n0 >= n1) return;
  float sc = ssc[lane], sh = ssc[64 + lane];
  float acc = 0.f;
  int cg = batch[n0];
  for (int n = n0; n < n1; n++) {
    int g = batch[n];
    if (g != cg) { atomicAdd(&pool[cg * 64 + lane], acc); acc = 0.f; cg = g; }
    float v = pre[(long long)n * 64 + lane] * sc + sh;
    v = v > 0.f ? v : (expf(v) - 1.f);
    nemb[(long long)n * 64 + lane] = v;
    acc += v;
  }
  atomicAdd(&pool[cg * 64 + lane], acc);
}

// ---------------- classifier + embedding head, one block per graph ----------------
__global__ void head_k(const float* __restrict__ pool, const int* __restrict__ batch,
                       const float* __restrict__ Wc1, const float* __restrict__ bc1,
                       const float* __restrict__ Wc2, const float* __restrict__ bc2,
                       const float* __restrict__ We, const float* __restrict__ bee,
                       float* __restrict__ logits, float* __restrict__ emb, int N) {
  int g = blockIdx.x, lane = threadIdx.x;  // 64 threads
  __shared__ float pr[64], hid[32];
  __shared__ int bnds[2];
  if (lane < 2) {
    int target = g + lane;  // lower_bound(batch, target)
    int lo = 0, hi = N;
    while (lo < hi) {
      int mid = (lo + hi) >> 1;
      if (batch[mid] < target) lo = mid + 1; else hi = mid;
    }
    bnds[lane] = lo;
  }
  __syncthreads();
  float cnt = (float)(bnds[1] - bnds[0]);
  pr[lane] = pool[g * 64 + lane] / fmaxf(cnt, 1.f);
  __syncthreads();
  if (lane < 32) {
    float a = bc1[lane];
    for (int k = 0; k < 64; k++) a += pr[k] * Wc1[k * 32 + lane];
    hid[lane] = fmaxf(a, 0.f);
  }
  float e = bee[lane];
  for (int k = 0; k < 64; k++) e += pr[k] * We[k * 64 + lane];
  emb[g * 64 + lane] = e;
  __syncthreads();
  if (lane < 2) {
    float l = bc2[lane];
    for (int k = 0; k < 32; k++) l += hid[k] * Wc2[k * 2 + lane];
    logits[g * 2 + lane] = l;
  }
}

extern "C" void kernel_launch(void* const* d_in, const int* in_sizes, int n_in,
                              void* d_out, int out_size, void* d_ws, size_t ws_size,
                              hipStream_t stream) {
  const float* x    = (const float*)d_in[0];
  const int*   ei   = (const int*)d_in[1];
  const int*   batch= (const int*)d_in[2];
  const float* W1   = (const float*)d_in[3];
  const float* as1  = (const float*)d_in[4];
  const float* ad1  = (const float*)d_in[5];
  const float* b1   = (const float*)d_in[6];
  const float* g1   = (const float*)d_in[7];
  const float* be1  = (const float*)d_in[8];
  const float* W2   = (const float*)d_in[9];
  const float* as2  = (const float*)d_in[10];
  const float* ad2  = (const float*)d_in[11];
  const float* b2   = (const float*)d_in[12];
  const float* g2   = (const float*)d_in[13];
  const float* be2  = (const float*)d_in[14];
  const float* W3   = (const float*)d_in[15];
  const float* as3  = (const float*)d_in[16];
  const float* ad3  = (const float*)d_in[17];
  const float* b3   = (const float*)d_in[18];
  const float* g3   = (const float*)d_in[19];
  const float* be3  = (const float*)d_in[20];
  const float* Wc1  = (const float*)d_in[21];
  const float* bc1  = (const float*)d_in[22];
  const float* Wc2  = (const float*)d_in[23];
  const float* bc2  = (const float*)d_in[24];
  const float* We   = (const float*)d_in[25];
  const float* bee  = (const float*)d_in[26];

  int N = in_sizes[0] / 12;
  int E = in_sizes[1] / 2;
  const int* srcv = ei;
  const int* dstv = ei + E;

  char* p = (char*)d_ws;
  auto carve = [&](size_t bytes) -> char* {
    char* r = p;
    p += (bytes + 255) & ~(size_t)255;
    return r;
  };
  int* counts  = (int*)carve((size_t)N * 4);
  int* cursor  = (int*)carve((size_t)N * 4);
  int* offs    = (int*)carve((size_t)(N + 1) * 4);
  int* bsums   = (int*)carve(4096 * 4);
  int* csr     = (int*)carve((size_t)E * 4);
  float* h     = (float*)carve((size_t)N * 64 * 4);
  float* als   = (float*)carve((size_t)N * 4 * 4);
  float* ald   = (float*)carve((size_t)N * 4 * 4);
  float* preA  = (float*)carve((size_t)N * 64 * 4);
  float* preB  = (float*)carve((size_t)N * 64 * 4);
  float* statsAll = (float*)carve(3 * 128 * 4);
  float* sscAll   = (float*)carve(3 * 128 * 4);
  float* poolbuf  = (float*)carve(64 * 64 * 4);

  hipMemsetAsync(counts, 0, (size_t)N * 4, stream);
  hipMemsetAsync(cursor, 0, (size_t)N * 4, stream);
  hipMemsetAsync(statsAll, 0, 3 * 128 * 4, stream);
  hipMemsetAsync(poolbuf, 0, 64 * 64 * 4, stream);

  int nbE = (E + THREADS - 1) / THREADS;
  int nbN = (N + THREADS - 1) / THREADS;
  hist_k<<<nbE, THREADS, 0, stream>>>(dstv, counts, E);
  scan1_k<<<nbN, THREADS, 0, stream>>>(counts, offs, bsums, N);
  scan2_k<<<1, 64, 0, stream>>>(bsums, nbN);
  scan3_k<<<nbN, THREADS, 0, stream>>>(offs, bsums, N, E);
  scatter_k<<<nbE, THREADS, 0, stream>>>(srcv, dstv, offs, cursor, csr, E);

  int nbNode = (N + 3) / 4;
  // ---- layer 1 (K=12, H=4) ----
  gat_transform<12, false><<<nbNode, THREADS, 0, stream>>>(x, nullptr, W1, as1, ad1, h, als, ald, N, 4);
  gat_gather<<<nbNode, THREADS, 0, stream>>>(h, als, ald, offs, csr, b1, preA, N, 4);
  bn_stats<<<1024, THREADS, 0, stream>>>(preA, statsAll + 0, N);
  bn_finalize<<<1, 64, 0, stream>>>(statsAll + 0, g1, be1, sscAll + 0, N);
  // ---- layer 2 (K=64, H=4) ----
  gat_transform<64, true><<<nbNode, THREADS, 0, stream>>>(preA, sscAll + 0, W2, as2, ad2, h, als, ald, N, 4);
  gat_gather<<<nbNode, THREADS, 0, stream>>>(h, als, ald, offs, csr, b2, preB, N, 4);
  bn_stats<<<1024, THREADS, 0, stream>>>(preB, statsAll + 128, N);
  bn_finalize<<<1, 64, 0, stream>>>(statsAll + 128, g2, be2, sscAll + 128, N);
  // ---- layer 3 (K=64, H=1) ----
  gat_transform<64, true><<<nbNode, THREADS, 0, stream>>>(preB, sscAll + 128, W3, as3, ad3, h, als, ald, N, 1);
  gat_gather<<<nbNode, THREADS, 0, stream>>>(h, als, ald, offs, csr, b3, preA, N, 1);
  bn_stats<<<1024, THREADS, 0, stream>>>(preA, statsAll + 256, N);
  bn_finalize<<<1, 64, 0, stream>>>(statsAll + 256, g3, be3, sscAll + 256, N);

  float* outF   = (float*)d_out;
  float* logits = outF;
  float* emb    = outF + 64 * 2;
  float* nemb   = outF + 64 * 2 + 64 * 64;

  // fused node-emb + pool partials: one wave per 128-node chunk
  const int PER = 128;
  int nWaves = (N + PER - 1) / PER;
  int nbPool = (nWaves + 3) / 4;
  emb_pool_k<<<nbPool, THREADS, 0, stream>>>(preA, sscAll + 256, batch, nemb, poolbuf, N, PER);
  head_k<<<64, 64, 0, stream>>>(poolbuf, batch, Wc1, bc1, Wc2, bc2, We, bee, logits, emb, N);
}

// Round 3
// 708.739 us; speedup vs baseline: 1.7925x; 1.2906x over previous
//
#include <hip/hip_runtime.h>
#include <math.h>

#define THREADS 256

// ---------------- CSR build ----------------
__global__ void hist_k(const int* __restrict__ dstv, int* __restrict__ counts, int E) {
  int i = blockIdx.x * THREADS + threadIdx.x;
  if (i < E) atomicAdd(&counts[dstv[i]], 1);
}

__global__ void scan1_k(const int* __restrict__ counts, int* __restrict__ offs,
                        int* __restrict__ bsums, int N) {
  __shared__ int s[THREADS];
  int i = blockIdx.x * THREADS + threadIdx.x;
  int v = (i < N) ? counts[i] : 0;
  s[threadIdx.x] = v;
  __syncthreads();
  for (int off = 1; off < THREADS; off <<= 1) {
    int t = (threadIdx.x >= off) ? s[threadIdx.x - off] : 0;
    __syncthreads();
    s[threadIdx.x] += t;
    __syncthreads();
  }
  if (i < N) offs[i] = s[threadIdx.x] - v;  // exclusive within block
  if (threadIdx.x == THREADS - 1) bsums[blockIdx.x] = s[THREADS - 1];
}

__global__ void scan2_k(int* bsums, int nb) {
  if (blockIdx.x == 0 && threadIdx.x == 0) {
    int run = 0;
    for (int b = 0; b < nb; b++) { int t = bsums[b]; bsums[b] = run; run += t; }
  }
}

__global__ void scan3_k(int* offs, const int* __restrict__ bsums, int N, int E) {
  int i = blockIdx.x * THREADS + threadIdx.x;
  if (i < N) offs[i] += bsums[blockIdx.x];
  if (i == 0) offs[N] = E;
}

__global__ void scatter_k(const int* __restrict__ srcv, const int* __restrict__ dstv,
                          const int* __restrict__ offs, int* __restrict__ cursor,
                          int* __restrict__ csr, int E) {
  int i = blockIdx.x * THREADS + threadIdx.x;
  if (i < E) {
    int d = dstv[i];
    int p = offs[d] + atomicAdd(&cursor[d], 1);
    csr[p] = srcv[i];
  }
}

// ---------------- GAT node transform: h = act(x) @ W, plus attention dots ----------------
template <int K, bool PRE>
__global__ void gat_transform(const float* __restrict__ xin, const float* __restrict__ ssc,
                              const float* __restrict__ W, const float* __restrict__ aS,
                              const float* __restrict__ aD, float* __restrict__ h,
                              float* __restrict__ als, float* __restrict__ ald,
                              int N, int H) {
  int wave = threadIdx.x >> 6;
  int lane = threadIdx.x & 63;
  int n = blockIdx.x * 4 + wave;
  __shared__ float xs[4][K];
  if (n < N && lane < K) {
    float v = xin[(long long)n * K + lane];
    if (PRE) {
      v = v * ssc[lane] + ssc[64 + lane];
      v = v > 0.f ? v : (__expf(v) - 1.f);  // ELU
    }
    xs[wave][lane] = v;
  }
  __syncthreads();
  if (n >= N) return;
  float acc = 0.f;
#pragma unroll
  for (int k = 0; k < K; k++) acc += xs[wave][k] * W[k * 64 + lane];
  h[(long long)n * 64 + lane] = acc;
  int C = 64 / H;
  float ts = acc * aS[lane], td = acc * aD[lane];
  for (int m = 1; m < C; m <<= 1) {
    ts += __shfl_xor(ts, m, 64);
    td += __shfl_xor(td, m, 64);
  }
  if ((lane & (C - 1)) == 0) {
    int hh = lane / C;
    als[(long long)n * H + hh] = ts;
    ald[(long long)n * H + hh] = td;
  }
}

// ---------------- Fused attention gather, two-phase per 64-edge tile ----------------
// Phase A: lanes = edges (parallel random als loads, shuffle-reduce max/sum per head).
// Phase B: lanes = channels (stream tile: acc += h[sn] * ex, loads pipelined).
template <int H>
__global__ void gat_gather2(const float* __restrict__ h, const float* __restrict__ als,
                            const float* __restrict__ ald, const int* __restrict__ offs,
                            const int* __restrict__ csr, const float* __restrict__ bias,
                            float* __restrict__ pre, int N) {
  constexpr int C = 64 / H;
  int wid = threadIdx.x >> 6, lane = threadIdx.x & 63;
  int n = blockIdx.x * 4 + wid;
  if (n >= N) return;
  __shared__ float lds_ex[4][64][H];
  __shared__ int lds_sn[4][64];

  float aldh[H], m[H], s[H];
#pragma unroll
  for (int t = 0; t < H; t++) {
    float av = als[(long long)n * H + t];
    aldh[t] = ald[(long long)n * H + t];
    float e = av + aldh[t];
    m[t] = e >= 0.f ? e : 0.2f * e;  // leaky_relu(0.2), self-loop seeds the max
    s[t] = 1.f;
  }
  int hh = lane / C;
  float acc = h[(long long)n * 64 + lane];  // self contribution at scale m
  int e0 = offs[n], e1 = offs[n + 1];

  for (int t0 = e0; t0 < e1; t0 += 64) {
    int idx = t0 + lane;
    bool act = idx < e1;
    int sn = act ? csr[idx] : 0;
    float ev[H];
    if (act) {
#pragma unroll
      for (int t = 0; t < H; t++) {
        float e = als[(long long)sn * H + t] + aldh[t];
        ev[t] = e >= 0.f ? e : 0.2f * e;
      }
    } else {
#pragma unroll
      for (int t = 0; t < H; t++) ev[t] = -1e30f;
    }
    // tile max per head across 64 lanes
    float tm[H];
#pragma unroll
    for (int t = 0; t < H; t++) tm[t] = ev[t];
#pragma unroll
    for (int ms = 1; ms < 64; ms <<= 1) {
#pragma unroll
      for (int t = 0; t < H; t++) tm[t] = fmaxf(tm[t], __shfl_xor(tm[t], ms, 64));
    }
    float r[H];
#pragma unroll
    for (int t = 0; t < H; t++) {
      float mn = fmaxf(m[t], tm[t]);
      r[t] = __expf(m[t] - mn);
      m[t] = mn;
    }
    float ex[H], ts[H];
#pragma unroll
    for (int t = 0; t < H; t++) ex[t] = act ? __expf(ev[t] - m[t]) : 0.f;
#pragma unroll
    for (int t = 0; t < H; t++) ts[t] = ex[t];
#pragma unroll
    for (int ms = 1; ms < 64; ms <<= 1) {
#pragma unroll
      for (int t = 0; t < H; t++) ts[t] += __shfl_xor(ts[t], ms, 64);
    }
#pragma unroll
    for (int t = 0; t < H; t++) s[t] = s[t] * r[t] + ts[t];
#pragma unroll
    for (int t = 0; t < H; t++) lds_ex[wid][lane][t] = ex[t];
    lds_sn[wid][lane] = sn;

    // Phase B: stream the tile
    acc *= r[hh];
    int cnt = e1 - t0; if (cnt > 64) cnt = 64;
#pragma unroll 4
    for (int j = 0; j < cnt; j++) {
      int sj = lds_sn[wid][j];
      acc += h[(long long)sj * 64 + lane] * lds_ex[wid][j][hh];
    }
  }
  pre[(long long)n * 64 + lane] = acc / (s[hh] + 1e-16f) + bias[lane];
}

// ---------------- BatchNorm statistics ----------------
__global__ void bn_stats(const float* __restrict__ x, float* __restrict__ stats, int N) {
  int tid = threadIdx.x;
  int f = tid & 63;
  long long total = (long long)N * 64;
  long long stride = (long long)gridDim.x * THREADS;
  float s = 0.f, q = 0.f;
  for (long long i = (long long)blockIdx.x * THREADS + tid; i < total; i += stride) {
    float v = x[i];
    s += v;
    q += v * v;
  }
  __shared__ float ls[THREADS], lq[THREADS];
  ls[tid] = s;
  lq[tid] = q;
  __syncthreads();
  if (tid < 64) {
    s = ls[tid] + ls[tid + 64] + ls[tid + 128] + ls[tid + 192];
    q = lq[tid] + lq[tid + 64] + lq[tid + 128] + lq[tid + 192];
    atomicAdd(&stats[f], s);
    atomicAdd(&stats[64 + f], q);
  }
}

__global__ void bn_finalize(const float* __restrict__ stats, const float* __restrict__ g,
                            const float* __restrict__ be, float* __restrict__ ssc, int N) {
  int f = threadIdx.x;  // 64 threads
  float inv = 1.f / (float)N;
  float mu = stats[f] * inv;
  float var = stats[64 + f] * inv - mu * mu;
  float rstd = rsqrtf(var + 1e-5f);
  float sc = rstd * g[f];
  ssc[f] = sc;
  ssc[64 + f] = be[f] - mu * sc;
}

// ---------------- fused: nemb = elu(bn(pre3)); pool partial sums via per-wave run ----------------
__global__ void emb_pool_k(const float* __restrict__ pre, const float* __restrict__ ssc,
                           const int* __restrict__ batch, float* __restrict__ nemb,
                           float* __restrict__ pool, int N, int per) {
  int lane = threadIdx.x & 63, wid = threadIdx.x >> 6;
  int gw = blockIdx.x * 4 + wid;
  int n0 = gw * per;
  int n1 = n0 + per; if (n1 > N) n1 = N;
  if (n0 >= n1) return;
  float sc = ssc[lane], sh = ssc[64 + lane];
  float acc = 0.f;
  int cg = batch[n0];
  for (int n = n0; n < n1; n++) {
    int g = batch[n];
    if (g != cg) { atomicAdd(&pool[cg * 64 + lane], acc); acc = 0.f; cg = g; }
    float v = pre[(long long)n * 64 + lane] * sc + sh;
    v = v > 0.f ? v : (__expf(v) - 1.f);
    nemb[(long long)n * 64 + lane] = v;
    acc += v;
  }
  atomicAdd(&pool[cg * 64 + lane], acc);
}

// ---------------- classifier + embedding head, one block per graph ----------------
__global__ void head_k(const float* __restrict__ pool, const int* __restrict__ batch,
                       const float* __restrict__ Wc1, const float* __restrict__ bc1,
                       const float* __restrict__ Wc2, const float* __restrict__ bc2,
                       const float* __restrict__ We, const float* __restrict__ bee,
                       float* __restrict__ logits, float* __restrict__ emb, int N) {
  int g = blockIdx.x, lane = threadIdx.x;  // 64 threads
  __shared__ float pr[64], hid[32];
  __shared__ int bnds[2];
  if (lane < 2) {
    int target = g + lane;  // lower_bound(batch, target)
    int lo = 0, hi = N;
    while (lo < hi) {
      int mid = (lo + hi) >> 1;
      if (batch[mid] < target) lo = mid + 1; else hi = mid;
    }
    bnds[lane] = lo;
  }
  __syncthreads();
  float cnt = (float)(bnds[1] - bnds[0]);
  pr[lane] = pool[g * 64 + lane] / fmaxf(cnt, 1.f);
  __syncthreads();
  if (lane < 32) {
    float a = bc1[lane];
    for (int k = 0; k < 64; k++) a += pr[k] * Wc1[k * 32 + lane];
    hid[lane] = fmaxf(a, 0.f);
  }
  float e = bee[lane];
  for (int k = 0; k < 64; k++) e += pr[k] * We[k * 64 + lane];
  emb[g * 64 + lane] = e;
  __syncthreads();
  if (lane < 2) {
    float l = bc2[lane];
    for (int k = 0; k < 32; k++) l += hid[k] * Wc2[k * 2 + lane];
    logits[g * 2 + lane] = l;
  }
}

extern "C" void kernel_launch(void* const* d_in, const int* in_sizes, int n_in,
                              void* d_out, int out_size, void* d_ws, size_t ws_size,
                              hipStream_t stream) {
  const float* x    = (const float*)d_in[0];
  const int*   ei   = (const int*)d_in[1];
  const int*   batch= (const int*)d_in[2];
  const float* W1   = (const float*)d_in[3];
  const float* as1  = (const float*)d_in[4];
  const float* ad1  = (const float*)d_in[5];
  const float* b1   = (const float*)d_in[6];
  const float* g1   = (const float*)d_in[7];
  const float* be1  = (const float*)d_in[8];
  const float* W2   = (const float*)d_in[9];
  const float* as2  = (const float*)d_in[10];
  const float* ad2  = (const float*)d_in[11];
  const float* b2   = (const float*)d_in[12];
  const float* g2   = (const float*)d_in[13];
  const float* be2  = (const float*)d_in[14];
  const float* W3   = (const float*)d_in[15];
  const float* as3  = (const float*)d_in[16];
  const float* ad3  = (const float*)d_in[17];
  const float* b3   = (const float*)d_in[18];
  const float* g3   = (const float*)d_in[19];
  const float* be3  = (const float*)d_in[20];
  const float* Wc1  = (const float*)d_in[21];
  const float* bc1  = (const float*)d_in[22];
  const float* Wc2  = (const float*)d_in[23];
  const float* bc2  = (const float*)d_in[24];
  const float* We   = (const float*)d_in[25];
  const float* bee  = (const float*)d_in[26];

  int N = in_sizes[0] / 12;
  int E = in_sizes[1] / 2;
  const int* srcv = ei;
  const int* dstv = ei + E;

  char* p = (char*)d_ws;
  auto carve = [&](size_t bytes) -> char* {
    char* r = p;
    p += (bytes + 255) & ~(size_t)255;
    return r;
  };
  int* counts  = (int*)carve((size_t)N * 4);
  int* cursor  = (int*)carve((size_t)N * 4);
  int* offs    = (int*)carve((size_t)(N + 1) * 4);
  int* bsums   = (int*)carve(4096 * 4);
  int* csr     = (int*)carve((size_t)E * 4);
  float* h     = (float*)carve((size_t)N * 64 * 4);
  float* als   = (float*)carve((size_t)N * 4 * 4);
  float* ald   = (float*)carve((size_t)N * 4 * 4);
  float* preA  = (float*)carve((size_t)N * 64 * 4);
  float* preB  = (float*)carve((size_t)N * 64 * 4);
  float* statsAll = (float*)carve(3 * 128 * 4);
  float* sscAll   = (float*)carve(3 * 128 * 4);
  float* poolbuf  = (float*)carve(64 * 64 * 4);

  hipMemsetAsync(counts, 0, (size_t)N * 4, stream);
  hipMemsetAsync(cursor, 0, (size_t)N * 4, stream);
  hipMemsetAsync(statsAll, 0, 3 * 128 * 4, stream);
  hipMemsetAsync(poolbuf, 0, 64 * 64 * 4, stream);

  int nbE = (E + THREADS - 1) / THREADS;
  int nbN = (N + THREADS - 1) / THREADS;
  hist_k<<<nbE, THREADS, 0, stream>>>(dstv, counts, E);
  scan1_k<<<nbN, THREADS, 0, stream>>>(counts, offs, bsums, N);
  scan2_k<<<1, 64, 0, stream>>>(bsums, nbN);
  scan3_k<<<nbN, THREADS, 0, stream>>>(offs, bsums, N, E);
  scatter_k<<<nbE, THREADS, 0, stream>>>(srcv, dstv, offs, cursor, csr, E);

  int nbNode = (N + 3) / 4;
  // ---- layer 1 (K=12, H=4) ----
  gat_transform<12, false><<<nbNode, THREADS, 0, stream>>>(x, nullptr, W1, as1, ad1, h, als, ald, N, 4);
  gat_gather2<4><<<nbNode, THREADS, 0, stream>>>(h, als, ald, offs, csr, b1, preA, N);
  bn_stats<<<1024, THREADS, 0, stream>>>(preA, statsAll + 0, N);
  bn_finalize<<<1, 64, 0, stream>>>(statsAll + 0, g1, be1, sscAll + 0, N);
  // ---- layer 2 (K=64, H=4) ----
  gat_transform<64, true><<<nbNode, THREADS, 0, stream>>>(preA, sscAll + 0, W2, as2, ad2, h, als, ald, N, 4);
  gat_gather2<4><<<nbNode, THREADS, 0, stream>>>(h, als, ald, offs, csr, b2, preB, N);
  bn_stats<<<1024, THREADS, 0, stream>>>(preB, statsAll + 128, N);
  bn_finalize<<<1, 64, 0, stream>>>(statsAll + 128, g2, be2, sscAll + 128, N);
  // ---- layer 3 (K=64, H=1) ----
  gat_transform<64, true><<<nbNode, THREADS, 0, stream>>>(preB, sscAll + 128, W3, as3, ad3, h, als, ald, N, 1);
  gat_gather2<1><<<nbNode, THREADS, 0, stream>>>(h, als, ald, offs, csr, b3, preA, N);
  bn_stats<<<1024, THREADS, 0, stream>>>(preA, statsAll + 256, N);
  bn_finalize<<<1, 64, 0, stream>>>(statsAll + 256, g3, be3, sscAll + 256, N);

  float* outF   = (float*)d_out;
  float* logits = outF;
  float* emb    = outF + 64 * 2;
  float* nemb   = outF + 64 * 2 + 64 * 64;

  const int PER = 128;
  int nWaves = (N + PER - 1) / PER;
  int nbPool = (nWaves + 3) / 4;
  emb_pool_k<<<nbPool, THREADS, 0, stream>>>(preA, sscAll + 256, batch, nemb, poolbuf, N, PER);
  head_k<<<64, 64, 0, stream>>>(poolbuf, batch, Wc1, bc1, Wc2, bc2, We, bee, logits, emb, N);
}

// Round 4
// 625.336 us; speedup vs baseline: 2.0316x; 1.1334x over previous
//
#include <hip/hip_runtime.h>
#include <hip/hip_bf16.h>
#include <math.h>

#define THREADS 256

__device__ __forceinline__ float lrelu02(float x) { return x >= 0.f ? x : 0.2f * x; }
__device__ __forceinline__ float b2f(__hip_bfloat16 v) { return __bfloat162float(v); }

// ---------------- CSR build ----------------
__global__ void hist_k(const int* __restrict__ dstv, int* __restrict__ counts, int E) {
  int i = blockIdx.x * THREADS + threadIdx.x;
  if (i < E) atomicAdd(&counts[dstv[i]], 1);
}

__global__ void scan1_k(const int* __restrict__ counts, int* __restrict__ offs,
                        int* __restrict__ bsums, int N) {
  __shared__ int s[THREADS];
  int i = blockIdx.x * THREADS + threadIdx.x;
  int v = (i < N) ? counts[i] : 0;
  s[threadIdx.x] = v;
  __syncthreads();
  for (int off = 1; off < THREADS; off <<= 1) {
    int t = (threadIdx.x >= off) ? s[threadIdx.x - off] : 0;
    __syncthreads();
    s[threadIdx.x] += t;
    __syncthreads();
  }
  if (i < N) offs[i] = s[threadIdx.x] - v;  // exclusive within block
  if (threadIdx.x == THREADS - 1) bsums[blockIdx.x] = s[THREADS - 1];
}

// parallel exclusive scan of block sums (nb <= 1024)
__global__ void scan2_k(int* bsums, int nb) {
  __shared__ int s[1024];
  int tid = threadIdx.x;
  int v = (tid < nb) ? bsums[tid] : 0;
  s[tid] = v;
  __syncthreads();
  for (int off = 1; off < 1024; off <<= 1) {
    int t = (tid >= off) ? s[tid - off] : 0;
    __syncthreads();
    s[tid] += t;
    __syncthreads();
  }
  if (tid < nb) bsums[tid] = s[tid] - v;
}

__global__ void scan3_k(int* offs, const int* __restrict__ bsums, int N, int E) {
  int i = blockIdx.x * THREADS + threadIdx.x;
  if (i < N) offs[i] += bsums[blockIdx.x];
  if (i == 0) offs[N] = E;
}

__global__ void scatter_k(const int* __restrict__ srcv, const int* __restrict__ dstv,
                          const int* __restrict__ offs, int* __restrict__ cursor,
                          int* __restrict__ csr, int E) {
  int i = blockIdx.x * THREADS + threadIdx.x;
  if (i < E) {
    int d = dstv[i];
    int p = offs[d] + atomicAdd(&cursor[d], 1);
    csr[p] = srcv[i];
  }
}

// ---------------- GAT node transform: h = act(x) @ W (bf16 out), attention dots fp32 ----------------
template <int K, bool PRE>
__global__ void gat_transform(const float* __restrict__ xin, const float* __restrict__ ssc,
                              const float* __restrict__ W, const float* __restrict__ aS,
                              const float* __restrict__ aD, __hip_bfloat16* __restrict__ h,
                              float* __restrict__ als, float* __restrict__ ald,
                              int N, int H) {
  int wave = threadIdx.x >> 6;
  int lane = threadIdx.x & 63;
  int n = blockIdx.x * 4 + wave;
  __shared__ float xs[4][K];
  if (n < N && lane < K) {
    float v = xin[(long long)n * K + lane];
    if (PRE) {
      v = v * ssc[lane] + ssc[64 + lane];
      v = v > 0.f ? v : (__expf(v) - 1.f);  // ELU
    }
    xs[wave][lane] = v;
  }
  __syncthreads();
  if (n >= N) return;
  float acc = 0.f;
#pragma unroll
  for (int k = 0; k < K; k++) acc += xs[wave][k] * W[k * 64 + lane];
  h[(long long)n * 64 + lane] = __float2bfloat16(acc);
  int C = 64 / H;
  float ts = acc * aS[lane], td = acc * aD[lane];
  for (int m = 1; m < C; m <<= 1) {
    ts += __shfl_xor(ts, m, 64);
    td += __shfl_xor(td, m, 64);
  }
  if ((lane & (C - 1)) == 0) {
    int hh = lane / C;
    als[(long long)n * H + hh] = ts;
    ald[(long long)n * H + hh] = td;
  }
}

// ---------------- Fused attention gather, H=4: lanes=(edge,head), 16 edges/pass ----------------
__global__ void gat_gather4(const __hip_bfloat16* __restrict__ h, const float* __restrict__ als,
                            const float* __restrict__ ald, const int* __restrict__ offs,
                            const int* __restrict__ csr, const float* __restrict__ bias,
                            float* __restrict__ pre, int N) {
  int wid = threadIdx.x >> 6, lane = threadIdx.x & 63;
  int n = blockIdx.x * 4 + wid;
  if (n >= N) return;
  __shared__ float lds_ex[4][64];  // [wid][e*4+t]
  __shared__ int lds_sn[4][16];

  int t = lane & 3;       // head (phase A)
  int e = lane >> 2;      // edge-in-tile 0..15 (phase A)
  int hh = lane >> 4;     // head (phase B, lane=channel)

  float aldt = ald[(long long)n * 4 + t];
  float m = lrelu02(als[(long long)n * 4 + t] + aldt);  // self-loop seeds max
  float s = 1.f;
  float acc = b2f(h[(long long)n * 64 + lane]);
  int e0 = offs[n], e1 = offs[n + 1];

  for (int t0 = e0; t0 < e1; t0 += 16) {
    int idx = t0 + e;
    bool act = idx < e1;
    int sn = act ? csr[idx] : 0;
    float ev = act ? lrelu02(als[(long long)sn * 4 + t] + aldt) : -1e30f;
    // max over the 16 edges (lanes differing in e-bits: masks 4,8,16,32)
    float tm = ev;
#pragma unroll
    for (int ms = 4; ms < 64; ms <<= 1) tm = fmaxf(tm, __shfl_xor(tm, ms, 64));
    float mn = fmaxf(m, tm);
    float r = __expf(m - mn);
    m = mn;
    float ex = act ? __expf(ev - m) : 0.f;
    float ts = ex;
#pragma unroll
    for (int ms = 4; ms < 64; ms <<= 1) ts += __shfl_xor(ts, ms, 64);
    s = s * r + ts;
    lds_ex[wid][lane] = ex;
    if (t == 0) lds_sn[wid][e] = sn;

    // Phase B: lanes = channels
    float rb = __shfl(r, hh, 64);  // lanes 0..3 hold heads 0..3
    acc *= rb;
    int cnt = e1 - t0; if (cnt > 16) cnt = 16;
#pragma unroll 4
    for (int j = 0; j < cnt; j++) {
      int sj = lds_sn[wid][j];
      acc += b2f(h[(long long)sj * 64 + lane]) * lds_ex[wid][(j << 2) + hh];
    }
  }
  float sb = __shfl(s, hh, 64);
  pre[(long long)n * 64 + lane] = acc / (sb + 1e-16f) + bias[lane];
}

// ---------------- Fused attention gather, H=1: lanes=edges, 64 edges/pass ----------------
__global__ void gat_gather1(const __hip_bfloat16* __restrict__ h, const float* __restrict__ als,
                            const float* __restrict__ ald, const int* __restrict__ offs,
                            const int* __restrict__ csr, const float* __restrict__ bias,
                            float* __restrict__ pre, int N) {
  int wid = threadIdx.x >> 6, lane = threadIdx.x & 63;
  int n = blockIdx.x * 4 + wid;
  if (n >= N) return;
  __shared__ float lds_ex[4][64];
  __shared__ int lds_sn[4][64];

  float aldn = ald[n];
  float m = lrelu02(als[n] + aldn);
  float s = 1.f;
  float acc = b2f(h[(long long)n * 64 + lane]);
  int e0 = offs[n], e1 = offs[n + 1];

  for (int t0 = e0; t0 < e1; t0 += 64) {
    int idx = t0 + lane;
    bool act = idx < e1;
    int sn = act ? csr[idx] : 0;
    float ev = act ? lrelu02(als[sn] + aldn) : -1e30f;
    float tm = ev;
#pragma unroll
    for (int ms = 1; ms < 64; ms <<= 1) tm = fmaxf(tm, __shfl_xor(tm, ms, 64));
    float mn = fmaxf(m, tm);
    float r = __expf(m - mn);
    m = mn;
    float ex = act ? __expf(ev - m) : 0.f;
    float ts = ex;
#pragma unroll
    for (int ms = 1; ms < 64; ms <<= 1) ts += __shfl_xor(ts, ms, 64);
    s = s * r + ts;
    lds_ex[wid][lane] = ex;
    lds_sn[wid][lane] = sn;

    acc *= r;
    int cnt = e1 - t0; if (cnt > 64) cnt = 64;
#pragma unroll 4
    for (int j = 0; j < cnt; j++) {
      int sj = lds_sn[wid][j];
      acc += b2f(h[(long long)sj * 64 + lane]) * lds_ex[wid][j];
    }
  }
  pre[(long long)n * 64 + lane] = acc / (s + 1e-16f) + bias[lane];
}

// ---------------- BatchNorm statistics ----------------
__global__ void bn_stats(const float* __restrict__ x, float* __restrict__ stats, int N) {
  int tid = threadIdx.x;
  int f = tid & 63;
  long long total = (long long)N * 64;
  long long stride = (long long)gridDim.x * THREADS;
  float s = 0.f, q = 0.f;
  for (long long i = (long long)blockIdx.x * THREADS + tid; i < total; i += stride) {
    float v = x[i];
    s += v;
    q += v * v;
  }
  __shared__ float ls[THREADS], lq[THREADS];
  ls[tid] = s;
  lq[tid] = q;
  __syncthreads();
  if (tid < 64) {
    s = ls[tid] + ls[tid + 64] + ls[tid + 128] + ls[tid + 192];
    q = lq[tid] + lq[tid + 64] + lq[tid + 128] + lq[tid + 192];
    atomicAdd(&stats[f], s);
    atomicAdd(&stats[64 + f], q);
  }
}

__global__ void bn_finalize(const float* __restrict__ stats, const float* __restrict__ g,
                            const float* __restrict__ be, float* __restrict__ ssc, int N) {
  int f = threadIdx.x;  // 64 threads
  float inv = 1.f / (float)N;
  float mu = stats[f] * inv;
  float var = stats[64 + f] * inv - mu * mu;
  float rstd = rsqrtf(var + 1e-5f);
  float sc = rstd * g[f];
  ssc[f] = sc;
  ssc[64 + f] = be[f] - mu * sc;
}

// ---------------- fused: nemb = elu(bn(pre3)); pool partial sums via per-wave run ----------------
__global__ void emb_pool_k(const float* __restrict__ pre, const float* __restrict__ ssc,
                           const int* __restrict__ batch, float* __restrict__ nemb,
                           float* __restrict__ pool, int N, int per) {
  int lane = threadIdx.x & 63, wid = threadIdx.x >> 6;
  int gw = blockIdx.x * 4 + wid;
  int n0 = gw * per;
  int n1 = n0 + per; if (n1 > N) n1 = N;
  if (n0 >= n1) return;
  float sc = ssc[lane], sh = ssc[64 + lane];
  float acc = 0.f;
  int cg = batch[n0];
  for (int n = n0; n < n1; n++) {
    int g = batch[n];
    if (g != cg) { atomicAdd(&pool[cg * 64 + lane], acc); acc = 0.f; cg = g; }
    float v = pre[(long long)n * 64 + lane] * sc + sh;
    v = v > 0.f ? v : (__expf(v) - 1.f);
    nemb[(long long)n * 64 + lane] = v;
    acc += v;
  }
  atomicAdd(&pool[cg * 64 + lane], acc);
}

// ---------------- classifier + embedding head, one block per graph ----------------
__global__ void head_k(const float* __restrict__ pool, const int* __restrict__ batch,
                       const float* __restrict__ Wc1, const float* __restrict__ bc1,
                       const float* __restrict__ Wc2, const float* __restrict__ bc2,
                       const float* __restrict__ We, const float* __restrict__ bee,
                       float* __restrict__ logits, float* __restrict__ emb, int N) {
  int g = blockIdx.x, lane = threadIdx.x;  // 64 threads
  __shared__ float pr[64], hid[32];
  __shared__ int bnds[2];
  if (lane < 2) {
    int target = g + lane;  // lower_bound(batch, target)
    int lo = 0, hi = N;
    while (lo < hi) {
      int mid = (lo + hi) >> 1;
      if (batch[mid] < target) lo = mid + 1; else hi = mid;
    }
    bnds[lane] = lo;
  }
  __syncthreads();
  float cnt = (float)(bnds[1] - bnds[0]);
  pr[lane] = pool[g * 64 + lane] / fmaxf(cnt, 1.f);
  __syncthreads();
  if (lane < 32) {
    float a = bc1[lane];
    for (int k = 0; k < 64; k++) a += pr[k] * Wc1[k * 32 + lane];
    hid[lane] = fmaxf(a, 0.f);
  }
  float e = bee[lane];
  for (int k = 0; k < 64; k++) e += pr[k] * We[k * 64 + lane];
  emb[g * 64 + lane] = e;
  __syncthreads();
  if (lane < 2) {
    float l = bc2[lane];
    for (int k = 0; k < 32; k++) l += hid[k] * Wc2[k * 2 + lane];
    logits[g * 2 + lane] = l;
  }
}

extern "C" void kernel_launch(void* const* d_in, const int* in_sizes, int n_in,
                              void* d_out, int out_size, void* d_ws, size_t ws_size,
                              hipStream_t stream) {
  const float* x    = (const float*)d_in[0];
  const int*   ei   = (const int*)d_in[1];
  const int*   batch= (const int*)d_in[2];
  const float* W1   = (const float*)d_in[3];
  const float* as1  = (const float*)d_in[4];
  const float* ad1  = (const float*)d_in[5];
  const float* b1   = (const float*)d_in[6];
  const float* g1   = (const float*)d_in[7];
  const float* be1  = (const float*)d_in[8];
  const float* W2   = (const float*)d_in[9];
  const float* as2  = (const float*)d_in[10];
  const float* ad2  = (const float*)d_in[11];
  const float* b2   = (const float*)d_in[12];
  const float* g2   = (const float*)d_in[13];
  const float* be2  = (const float*)d_in[14];
  const float* W3   = (const float*)d_in[15];
  const float* as3  = (const float*)d_in[16];
  const float* ad3  = (const float*)d_in[17];
  const float* b3   = (const float*)d_in[18];
  const float* g3   = (const float*)d_in[19];
  const float* be3  = (const float*)d_in[20];
  const float* Wc1  = (const float*)d_in[21];
  const float* bc1  = (const float*)d_in[22];
  const float* Wc2  = (const float*)d_in[23];
  const float* bc2  = (const float*)d_in[24];
  const float* We   = (const float*)d_in[25];
  const float* bee  = (const float*)d_in[26];

  int N = in_sizes[0] / 12;
  int E = in_sizes[1] / 2;
  const int* srcv = ei;
  const int* dstv = ei + E;

  char* p = (char*)d_ws;
  auto carve = [&](size_t bytes) -> char* {
    char* r = p;
    p += (bytes + 255) & ~(size_t)255;
    return r;
  };
  int* counts  = (int*)carve((size_t)N * 4);
  int* cursor  = (int*)carve((size_t)N * 4);
  int* offs    = (int*)carve((size_t)(N + 1) * 4);
  int* bsums   = (int*)carve(4096 * 4);
  int* csr     = (int*)carve((size_t)E * 4);
  __hip_bfloat16* h = (__hip_bfloat16*)carve((size_t)N * 64 * 2);
  float* als   = (float*)carve((size_t)N * 4 * 4);
  float* ald   = (float*)carve((size_t)N * 4 * 4);
  float* preA  = (float*)carve((size_t)N * 64 * 4);
  float* preB  = (float*)carve((size_t)N * 64 * 4);
  float* statsAll = (float*)carve(3 * 128 * 4);
  float* sscAll   = (float*)carve(3 * 128 * 4);
  float* poolbuf  = (float*)carve(64 * 64 * 4);

  hipMemsetAsync(counts, 0, (size_t)N * 4, stream);
  hipMemsetAsync(cursor, 0, (size_t)N * 4, stream);
  hipMemsetAsync(statsAll, 0, 3 * 128 * 4, stream);
  hipMemsetAsync(poolbuf, 0, 64 * 64 * 4, stream);

  int nbE = (E + THREADS - 1) / THREADS;
  int nbN = (N + THREADS - 1) / THREADS;
  hist_k<<<nbE, THREADS, 0, stream>>>(dstv, counts, E);
  scan1_k<<<nbN, THREADS, 0, stream>>>(counts, offs, bsums, N);
  scan2_k<<<1, 1024, 0, stream>>>(bsums, nbN);
  scan3_k<<<nbN, THREADS, 0, stream>>>(offs, bsums, N, E);
  scatter_k<<<nbE, THREADS, 0, stream>>>(srcv, dstv, offs, cursor, csr, E);

  int nbNode = (N + 3) / 4;
  // ---- layer 1 (K=12, H=4) ----
  gat_transform<12, false><<<nbNode, THREADS, 0, stream>>>(x, nullptr, W1, as1, ad1, h, als, ald, N, 4);
  gat_gather4<<<nbNode, THREADS, 0, stream>>>(h, als, ald, offs, csr, b1, preA, N);
  bn_stats<<<1024, THREADS, 0, stream>>>(preA, statsAll + 0, N);
  bn_finalize<<<1, 64, 0, stream>>>(statsAll + 0, g1, be1, sscAll + 0, N);
  // ---- layer 2 (K=64, H=4) ----
  gat_transform<64, true><<<nbNode, THREADS, 0, stream>>>(preA, sscAll + 0, W2, as2, ad2, h, als, ald, N, 4);
  gat_gather4<<<nbNode, THREADS, 0, stream>>>(h, als, ald, offs, csr, b2, preB, N);
  bn_stats<<<1024, THREADS, 0, stream>>>(preB, statsAll + 128, N);
  bn_finalize<<<1, 64, 0, stream>>>(statsAll + 128, g2, be2, sscAll + 128, N);
  // ---- layer 3 (K=64, H=1) ----
  gat_transform<64, true><<<nbNode, THREADS, 0, stream>>>(preB, sscAll + 128, W3, as3, ad3, h, als, ald, N, 1);
  gat_gather1<<<nbNode, THREADS, 0, stream>>>(h, als, ald, offs, csr, b3, preA, N);
  bn_stats<<<1024, THREADS, 0, stream>>>(preA, statsAll + 256, N);
  bn_finalize<<<1, 64, 0, stream>>>(statsAll + 256, g3, be3, sscAll + 256, N);

  float* outF   = (float*)d_out;
  float* logits = outF;
  float* emb    = outF + 64 * 2;
  float* nemb   = outF + 64 * 2 + 64 * 64;

  const int PER = 128;
  int nWaves = (N + PER - 1) / PER;
  int nbPool = (nWaves + 3) / 4;
  emb_pool_k<<<nbPool, THREADS, 0, stream>>>(preA, sscAll + 256, batch, nemb, poolbuf, N, PER);
  head_k<<<64, 64, 0, stream>>>(poolbuf, batch, Wc1, bc1, Wc2, bc2, We, bee, logits, emb, N);
}

// Round 5
// 620.195 us; speedup vs baseline: 2.0484x; 1.0083x over previous
//
#include <hip/hip_runtime.h>
#include <hip/hip_bf16.h>
#include <math.h>

#define THREADS 256

__device__ __forceinline__ float lrelu02(float x) { return x >= 0.f ? x : 0.2f * x; }
__device__ __forceinline__ float b2f(__hip_bfloat16 v) { return __bfloat162float(v); }

// ---------------- CSR build (XCD-partitioned: blockIdx%8 -> dst range) ----------------
// Blocks round-robin across XCDs; restricting each residue class to one dst
// range keeps counts/cursor/csr lines dirty in exactly one XCD's L2.
__global__ void hist8_k(const int* __restrict__ dstv, int* __restrict__ counts,
                        int E, int RS) {
  int s = blockIdx.x & 7;
  int i = (blockIdx.x >> 3) * THREADS + threadIdx.x;
  if (i >= E) return;
  int d = dstv[i];
  int lo = s * RS;
  if (d >= lo && d < lo + RS) atomicAdd(&counts[d], 1);
}

__global__ void scatter8_k(const int* __restrict__ srcv, const int* __restrict__ dstv,
                           const int* __restrict__ offs, int* __restrict__ cursor,
                           int* __restrict__ csr, int E, int RS) {
  int s = blockIdx.x & 7;
  int i = (blockIdx.x >> 3) * THREADS + threadIdx.x;
  if (i >= E) return;
  int d = dstv[i];
  int lo = s * RS;
  if (d >= lo && d < lo + RS) {
    int p = offs[d] + atomicAdd(&cursor[d], 1);
    csr[p] = srcv[i];
  }
}

__global__ void scan1_k(const int* __restrict__ counts, int* __restrict__ offs,
                        int* __restrict__ bsums, int N) {
  __shared__ int s[THREADS];
  int i = blockIdx.x * THREADS + threadIdx.x;
  int v = (i < N) ? counts[i] : 0;
  s[threadIdx.x] = v;
  __syncthreads();
  for (int off = 1; off < THREADS; off <<= 1) {
    int t = (threadIdx.x >= off) ? s[threadIdx.x - off] : 0;
    __syncthreads();
    s[threadIdx.x] += t;
    __syncthreads();
  }
  if (i < N) offs[i] = s[threadIdx.x] - v;  // exclusive within block
  if (threadIdx.x == THREADS - 1) bsums[blockIdx.x] = s[THREADS - 1];
}

// parallel exclusive scan of block sums (nb <= 1024)
__global__ void scan2_k(int* bsums, int nb) {
  __shared__ int s[1024];
  int tid = threadIdx.x;
  int v = (tid < nb) ? bsums[tid] : 0;
  s[tid] = v;
  __syncthreads();
  for (int off = 1; off < 1024; off <<= 1) {
    int t = (tid >= off) ? s[tid - off] : 0;
    __syncthreads();
    s[tid] += t;
    __syncthreads();
  }
  if (tid < nb) bsums[tid] = s[tid] - v;
}

__global__ void scan3_k(int* offs, const int* __restrict__ bsums, int N, int E) {
  int i = blockIdx.x * THREADS + threadIdx.x;
  if (i < N) offs[i] += bsums[blockIdx.x];
  if (i == 0) offs[N] = E;
}

// ---------------- GAT node transform: h = act(x) @ W (bf16 out), attention dots fp32 ----------------
template <int K, bool PRE>
__global__ void gat_transform(const float* __restrict__ xin, const float* __restrict__ ssc,
                              const float* __restrict__ W, const float* __restrict__ aS,
                              const float* __restrict__ aD, __hip_bfloat16* __restrict__ h,
                              float* __restrict__ als, float* __restrict__ ald,
                              int N, int H) {
  int wave = threadIdx.x >> 6;
  int lane = threadIdx.x & 63;
  int n = blockIdx.x * 4 + wave;
  __shared__ float xs[4][K];
  if (n < N && lane < K) {
    float v = xin[(long long)n * K + lane];
    if (PRE) {
      v = v * ssc[lane] + ssc[64 + lane];
      v = v > 0.f ? v : (__expf(v) - 1.f);  // ELU
    }
    xs[wave][lane] = v;
  }
  __syncthreads();
  if (n >= N) return;
  float acc = 0.f;
#pragma unroll
  for (int k = 0; k < K; k++) acc += xs[wave][k] * W[k * 64 + lane];
  h[(long long)n * 64 + lane] = __float2bfloat16(acc);
  int C = 64 / H;
  float ts = acc * aS[lane], td = acc * aD[lane];
  for (int m = 1; m < C; m <<= 1) {
    ts += __shfl_xor(ts, m, 64);
    td += __shfl_xor(td, m, 64);
  }
  if ((lane & (C - 1)) == 0) {
    int hh = lane / C;
    als[(long long)n * H + hh] = ts;
    ald[(long long)n * H + hh] = td;
  }
}

// ---------------- Fused attention gather, H=4: lanes=(edge,head), 16 edges/pass ----------------
__global__ void gat_gather4(const __hip_bfloat16* __restrict__ h, const float* __restrict__ als,
                            const float* __restrict__ ald, const int* __restrict__ offs,
                            const int* __restrict__ csr, const float* __restrict__ bias,
                            float* __restrict__ pre, int N) {
  int wid = threadIdx.x >> 6, lane = threadIdx.x & 63;
  int n = blockIdx.x * 4 + wid;
  if (n >= N) return;
  __shared__ float lds_ex[4][64];  // [wid][e*4+t]
  __shared__ int lds_sn[4][16];

  int t = lane & 3;       // head (phase A)
  int e = lane >> 2;      // edge-in-tile 0..15 (phase A)
  int hh = lane >> 4;     // head (phase B, lane=channel)

  float aldt = ald[(long long)n * 4 + t];
  float m = lrelu02(als[(long long)n * 4 + t] + aldt);  // self-loop seeds max
  float s = 1.f;
  float acc = b2f(h[(long long)n * 64 + lane]);
  int e0 = offs[n], e1 = offs[n + 1];

  for (int t0 = e0; t0 < e1; t0 += 16) {
    int idx = t0 + e;
    bool act = idx < e1;
    int sn = act ? csr[idx] : 0;
    float ev = act ? lrelu02(als[(long long)sn * 4 + t] + aldt) : -1e30f;
    // max over the 16 edges (lanes differing in e-bits: masks 4,8,16,32)
    float tm = ev;
#pragma unroll
    for (int ms = 4; ms < 64; ms <<= 1) tm = fmaxf(tm, __shfl_xor(tm, ms, 64));
    float mn = fmaxf(m, tm);
    float r = __expf(m - mn);
    m = mn;
    float ex = act ? __expf(ev - m) : 0.f;
    float ts = ex;
#pragma unroll
    for (int ms = 4; ms < 64; ms <<= 1) ts += __shfl_xor(ts, ms, 64);
    s = s * r + ts;
    lds_ex[wid][lane] = ex;
    if (t == 0) lds_sn[wid][e] = sn;

    // Phase B: lanes = channels
    float rb = __shfl(r, hh, 64);  // lanes 0..3 hold heads 0..3
    acc *= rb;
    int cnt = e1 - t0; if (cnt > 16) cnt = 16;
#pragma unroll 4
    for (int j = 0; j < cnt; j++) {
      int sj = lds_sn[wid][j];
      acc += b2f(h[(long long)sj * 64 + lane]) * lds_ex[wid][(j << 2) + hh];
    }
  }
  float sb = __shfl(s, hh, 64);
  pre[(long long)n * 64 + lane] = acc / (sb + 1e-16f) + bias[lane];
}

// ---------------- Fused attention gather, H=1: lanes=edges, 64 edges/pass ----------------
__global__ void gat_gather1(const __hip_bfloat16* __restrict__ h, const float* __restrict__ als,
                            const float* __restrict__ ald, const int* __restrict__ offs,
                            const int* __restrict__ csr, const float* __restrict__ bias,
                            float* __restrict__ pre, int N) {
  int wid = threadIdx.x >> 6, lane = threadIdx.x & 63;
  int n = blockIdx.x * 4 + wid;
  if (n >= N) return;
  __shared__ float lds_ex[4][64];
  __shared__ int lds_sn[4][64];

  float aldn = ald[n];
  float m = lrelu02(als[n] + aldn);
  float s = 1.f;
  float acc = b2f(h[(long long)n * 64 + lane]);
  int e0 = offs[n], e1 = offs[n + 1];

  for (int t0 = e0; t0 < e1; t0 += 64) {
    int idx = t0 + lane;
    bool act = idx < e1;
    int sn = act ? csr[idx] : 0;
    float ev = act ? lrelu02(als[sn] + aldn) : -1e30f;
    float tm = ev;
#pragma unroll
    for (int ms = 1; ms < 64; ms <<= 1) tm = fmaxf(tm, __shfl_xor(tm, ms, 64));
    float mn = fmaxf(m, tm);
    float r = __expf(m - mn);
    m = mn;
    float ex = act ? __expf(ev - m) : 0.f;
    float ts = ex;
#pragma unroll
    for (int ms = 1; ms < 64; ms <<= 1) ts += __shfl_xor(ts, ms, 64);
    s = s * r + ts;
    lds_ex[wid][lane] = ex;
    lds_sn[wid][lane] = sn;

    acc *= r;
    int cnt = e1 - t0; if (cnt > 64) cnt = 64;
#pragma unroll 4
    for (int j = 0; j < cnt; j++) {
      int sj = lds_sn[wid][j];
      acc += b2f(h[(long long)sj * 64 + lane]) * lds_ex[wid][j];
    }
  }
  pre[(long long)n * 64 + lane] = acc / (s + 1e-16f) + bias[lane];
}

// ---------------- BatchNorm statistics ----------------
__global__ void bn_stats(const float* __restrict__ x, float* __restrict__ stats, int N) {
  int tid = threadIdx.x;
  int f = tid & 63;
  long long total = (long long)N * 64;
  long long stride = (long long)gridDim.x * THREADS;
  float s = 0.f, q = 0.f;
  for (long long i = (long long)blockIdx.x * THREADS + tid; i < total; i += stride) {
    float v = x[i];
    s += v;
    q += v * v;
  }
  __shared__ float ls[THREADS], lq[THREADS];
  ls[tid] = s;
  lq[tid] = q;
  __syncthreads();
  if (tid < 64) {
    s = ls[tid] + ls[tid + 64] + ls[tid + 128] + ls[tid + 192];
    q = lq[tid] + lq[tid + 64] + lq[tid + 128] + lq[tid + 192];
    atomicAdd(&stats[f], s);
    atomicAdd(&stats[64 + f], q);
  }
}

__global__ void bn_finalize(const float* __restrict__ stats, const float* __restrict__ g,
                            const float* __restrict__ be, float* __restrict__ ssc, int N) {
  int f = threadIdx.x;  // 64 threads
  float inv = 1.f / (float)N;
  float mu = stats[f] * inv;
  float var = stats[64 + f] * inv - mu * mu;
  float rstd = rsqrtf(var + 1e-5f);
  float sc = rstd * g[f];
  ssc[f] = sc;
  ssc[64 + f] = be[f] - mu * sc;
}

// ---------------- fused: nemb = elu(bn(pre3)); pool partial sums via per-wave run ----------------
__global__ void emb_pool_k(const float* __restrict__ pre, const float* __restrict__ ssc,
                           const int* __restrict__ batch, float* __restrict__ nemb,
                           float* __restrict__ pool, int N, int per) {
  int lane = threadIdx.x & 63, wid = threadIdx.x >> 6;
  int gw = blockIdx.x * 4 + wid;
  int n0 = gw * per;
  int n1 = n0 + per; if (n1 > N) n1 = N;
  if (n0 >= n1) return;
  float sc = ssc[lane], sh = ssc[64 + lane];
  float acc = 0.f;
  int cg = batch[n0];
  for (int n = n0; n < n1; n++) {
    int g = batch[n];
    if (g != cg) { atomicAdd(&pool[cg * 64 + lane], acc); acc = 0.f; cg = g; }
    float v = pre[(long long)n * 64 + lane] * sc + sh;
    v = v > 0.f ? v : (__expf(v) - 1.f);
    nemb[(long long)n * 64 + lane] = v;
    acc += v;
  }
  atomicAdd(&pool[cg * 64 + lane], acc);
}

// ---------------- classifier + embedding head, one block per graph ----------------
__global__ void head_k(const float* __restrict__ pool, const int* __restrict__ batch,
                       const float* __restrict__ Wc1, const float* __restrict__ bc1,
                       const float* __restrict__ Wc2, const float* __restrict__ bc2,
                       const float* __restrict__ We, const float* __restrict__ bee,
                       float* __restrict__ logits, float* __restrict__ emb, int N) {
  int g = blockIdx.x, lane = threadIdx.x;  // 64 threads
  __shared__ float pr[64], hid[32];
  __shared__ int bnds[2];
  if (lane < 2) {
    int target = g + lane;  // lower_bound(batch, target)
    int lo = 0, hi = N;
    while (lo < hi) {
      int mid = (lo + hi) >> 1;
      if (batch[mid] < target) lo = mid + 1; else hi = mid;
    }
    bnds[lane] = lo;
  }
  __syncthreads();
  float cnt = (float)(bnds[1] - bnds[0]);
  pr[lane] = pool[g * 64 + lane] / fmaxf(cnt, 1.f);
  __syncthreads();
  if (lane < 32) {
    float a = bc1[lane];
    for (int k = 0; k < 64; k++) a += pr[k] * Wc1[k * 32 + lane];
    hid[lane] = fmaxf(a, 0.f);
  }
  float e = bee[lane];
  for (int k = 0; k < 64; k++) e += pr[k] * We[k * 64 + lane];
  emb[g * 64 + lane] = e;
  __syncthreads();
  if (lane < 2) {
    float l = bc2[lane];
    for (int k = 0; k < 32; k++) l += hid[k] * Wc2[k * 2 + lane];
    logits[g * 2 + lane] = l;
  }
}

extern "C" void kernel_launch(void* const* d_in, const int* in_sizes, int n_in,
                              void* d_out, int out_size, void* d_ws, size_t ws_size,
                              hipStream_t stream) {
  const float* x    = (const float*)d_in[0];
  const int*   ei   = (const int*)d_in[1];
  const int*   batch= (const int*)d_in[2];
  const float* W1   = (const float*)d_in[3];
  const float* as1  = (const float*)d_in[4];
  const float* ad1  = (const float*)d_in[5];
  const float* b1   = (const float*)d_in[6];
  const float* g1   = (const float*)d_in[7];
  const float* be1  = (const float*)d_in[8];
  const float* W2   = (const float*)d_in[9];
  const float* as2  = (const float*)d_in[10];
  const float* ad2  = (const float*)d_in[11];
  const float* b2   = (const float*)d_in[12];
  const float* g2   = (const float*)d_in[13];
  const float* be2  = (const float*)d_in[14];
  const float* W3   = (const float*)d_in[15];
  const float* as3  = (const float*)d_in[16];
  const float* ad3  = (const float*)d_in[17];
  const float* b3   = (const float*)d_in[18];
  const float* g3   = (const float*)d_in[19];
  const float* be3  = (const float*)d_in[20];
  const float* Wc1  = (const float*)d_in[21];
  const float* bc1  = (const float*)d_in[22];
  const float* Wc2  = (const float*)d_in[23];
  const float* bc2  = (const float*)d_in[24];
  const float* We   = (const float*)d_in[25];
  const float* bee  = (const float*)d_in[26];

  int N = in_sizes[0] / 12;
  int E = in_sizes[1] / 2;
  const int* srcv = ei;
  const int* dstv = ei + E;

  char* p = (char*)d_ws;
  auto carve = [&](size_t bytes) -> char* {
    char* r = p;
    p += (bytes + 255) & ~(size_t)255;
    return r;
  };
  int* counts  = (int*)carve((size_t)N * 4);
  int* cursor  = (int*)carve((size_t)N * 4);
  int* offs    = (int*)carve((size_t)(N + 1) * 4);
  int* bsums   = (int*)carve(4096 * 4);
  int* csr     = (int*)carve((size_t)E * 4);
  __hip_bfloat16* h = (__hip_bfloat16*)carve((size_t)N * 64 * 2);
  float* als   = (float*)carve((size_t)N * 4 * 4);
  float* ald   = (float*)carve((size_t)N * 4 * 4);
  float* preA  = (float*)carve((size_t)N * 64 * 4);
  float* preB  = (float*)carve((size_t)N * 64 * 4);
  float* statsAll = (float*)carve(3 * 128 * 4);
  float* sscAll   = (float*)carve(3 * 128 * 4);
  float* poolbuf  = (float*)carve(64 * 64 * 4);

  hipMemsetAsync(counts, 0, (size_t)N * 4, stream);
  hipMemsetAsync(cursor, 0, (size_t)N * 4, stream);
  hipMemsetAsync(statsAll, 0, 3 * 128 * 4, stream);
  hipMemsetAsync(poolbuf, 0, 64 * 64 * 4, stream);

  int nbE = (E + THREADS - 1) / THREADS;
  int nbN = (N + THREADS - 1) / THREADS;
  int RS = (N + 7) / 8;  // dst-range size per XCD residue class
  hist8_k<<<nbE * 8, THREADS, 0, stream>>>(dstv, counts, E, RS);
  scan1_k<<<nbN, THREADS, 0, stream>>>(counts, offs, bsums, N);
  scan2_k<<<1, 1024, 0, stream>>>(bsums, nbN);
  scan3_k<<<nbN, THREADS, 0, stream>>>(offs, bsums, N, E);
  scatter8_k<<<nbE * 8, THREADS, 0, stream>>>(srcv, dstv, offs, cursor, csr, E, RS);

  int nbNode = (N + 3) / 4;
  // ---- layer 1 (K=12, H=4) ----
  gat_transform<12, false><<<nbNode, THREADS, 0, stream>>>(x, nullptr, W1, as1, ad1, h, als, ald, N, 4);
  gat_gather4<<<nbNode, THREADS, 0, stream>>>(h, als, ald, offs, csr, b1, preA, N);
  bn_stats<<<1024, THREADS, 0, stream>>>(preA, statsAll + 0, N);
  bn_finalize<<<1, 64, 0, stream>>>(statsAll + 0, g1, be1, sscAll + 0, N);
  // ---- layer 2 (K=64, H=4) ----
  gat_transform<64, true><<<nbNode, THREADS, 0, stream>>>(preA, sscAll + 0, W2, as2, ad2, h, als, ald, N, 4);
  gat_gather4<<<nbNode, THREADS, 0, stream>>>(h, als, ald, offs, csr, b2, preB, N);
  bn_stats<<<1024, THREADS, 0, stream>>>(preB, statsAll + 128, N);
  bn_finalize<<<1, 64, 0, stream>>>(statsAll + 128, g2, be2, sscAll + 128, N);
  // ---- layer 3 (K=64, H=1) ----
  gat_transform<64, true><<<nbNode, THREADS, 0, stream>>>(preB, sscAll + 128, W3, as3, ad3, h, als, ald, N, 1);
  gat_gather1<<<nbNode, THREADS, 0, stream>>>(h, als, ald, offs, csr, b3, preA, N);
  bn_stats<<<1024, THREADS, 0, stream>>>(preA, statsAll + 256, N);
  bn_finalize<<<1, 64, 0, stream>>>(statsAll + 256, g3, be3, sscAll + 256, N);

  float* outF   = (float*)d_out;
  float* logits = outF;
  float* emb    = outF + 64 * 2;
  float* nemb   = outF + 64 * 2 + 64 * 64;

  const int PER = 128;
  int nWaves = (N + PER - 1) / PER;
  int nbPool = (nWaves + 3) / 4;
  emb_pool_k<<<nbPool, THREADS, 0, stream>>>(preA, sscAll + 256, batch, nemb, poolbuf, N, PER);
  head_k<<<64, 64, 0, stream>>>(poolbuf, batch, Wc1, bc1, Wc2, bc2, We, bee, logits, emb, N);
}

// Round 6
// 553.813 us; speedup vs baseline: 2.2939x; 1.1199x over previous
//
#include <hip/hip_runtime.h>
#include <hip/hip_bf16.h>
#include <math.h>

#define THREADS 256

__device__ __forceinline__ float lrelu02(float x) { return x >= 0.f ? x : 0.2f * x; }
__device__ __forceinline__ float b2f(__hip_bfloat16 v) { return __bfloat162float(v); }

// ---------------- CSR build ----------------
__global__ void hist_k(const int* __restrict__ dstv, int* __restrict__ counts, int E) {
  int i = blockIdx.x * THREADS + threadIdx.x;
  if (i < E) atomicAdd(&counts[dstv[i]], 1);
}

// XCD-partitioned scatter: blockIdx%8 ~ XCD id (round-robin dispatch heuristic);
// each residue class owns one dst range so csr/cursor lines stay in one L2.
__global__ void scatter8_k(const int* __restrict__ srcv, const int* __restrict__ dstv,
                           int* __restrict__ cursor, int* __restrict__ csr,
                           int E, int RS) {
  int s = blockIdx.x & 7;
  int i = (blockIdx.x >> 3) * THREADS + threadIdx.x;
  if (i >= E) return;
  int d = dstv[i];
  int lo = s * RS;
  if (d >= lo && d < lo + RS) {
    int p = atomicAdd(&cursor[d], 1);
    csr[p] = srcv[i];
  }
}

__global__ void scan1_k(const int* __restrict__ counts, int* __restrict__ offs,
                        int* __restrict__ bsums, int N) {
  __shared__ int s[THREADS];
  int i = blockIdx.x * THREADS + threadIdx.x;
  int v = (i < N) ? counts[i] : 0;
  s[threadIdx.x] = v;
  __syncthreads();
  for (int off = 1; off < THREADS; off <<= 1) {
    int t = (threadIdx.x >= off) ? s[threadIdx.x - off] : 0;
    __syncthreads();
    s[threadIdx.x] += t;
    __syncthreads();
  }
  if (i < N) offs[i] = s[threadIdx.x] - v;  // exclusive within block
  if (threadIdx.x == THREADS - 1) bsums[blockIdx.x] = s[THREADS - 1];
}

// parallel exclusive scan of block sums (nb <= 1024)
__global__ void scan2_k(int* bsums, int nb) {
  __shared__ int s[1024];
  int tid = threadIdx.x;
  int v = (tid < nb) ? bsums[tid] : 0;
  s[tid] = v;
  __syncthreads();
  for (int off = 1; off < 1024; off <<= 1) {
    int t = (tid >= off) ? s[tid - off] : 0;
    __syncthreads();
    s[tid] += t;
    __syncthreads();
  }
  if (tid < nb) bsums[tid] = s[tid] - v;
}

__global__ void scan3_k(int* offs, int* __restrict__ cursor,
                        const int* __restrict__ bsums, int N, int E) {
  int i = blockIdx.x * THREADS + threadIdx.x;
  if (i < N) {
    int v = offs[i] + bsums[blockIdx.x];
    offs[i] = v;
    cursor[i] = v;  // scatter cursor starts at row offset
  }
  if (i == 0) offs[N] = E;
}

// ---------------- GAT node transform: h = act(x) @ W (bf16 out), attention dots fp32 ----------------
template <int K, bool PRE>
__global__ void gat_transform(const float* __restrict__ xin, const float* __restrict__ ssc,
                              const float* __restrict__ W, const float* __restrict__ aS,
                              const float* __restrict__ aD, __hip_bfloat16* __restrict__ h,
                              float* __restrict__ als, float* __restrict__ ald,
                              int N, int H) {
  int wave = threadIdx.x >> 6;
  int lane = threadIdx.x & 63;
  int n = blockIdx.x * 4 + wave;
  __shared__ float xs[4][K];
  if (n < N && lane < K) {
    float v = xin[(long long)n * K + lane];
    if (PRE) {
      v = v * ssc[lane] + ssc[64 + lane];
      v = v > 0.f ? v : (__expf(v) - 1.f);  // ELU
    }
    xs[wave][lane] = v;
  }
  __syncthreads();
  if (n >= N) return;
  float acc = 0.f;
#pragma unroll
  for (int k = 0; k < K; k++) acc += xs[wave][k] * W[k * 64 + lane];
  h[(long long)n * 64 + lane] = __float2bfloat16(acc);
  int C = 64 / H;
  float ts = acc * aS[lane], td = acc * aD[lane];
  for (int m = 1; m < C; m <<= 1) {
    ts += __shfl_xor(ts, m, 64);
    td += __shfl_xor(td, m, 64);
  }
  if ((lane & (C - 1)) == 0) {
    int hh = lane / C;
    als[(long long)n * H + hh] = ts;
    ald[(long long)n * H + hh] = td;
  }
}

// ---------------- Attention gather, H=4, no-max softmax (logits provably tiny) ----------------
// lanes=(edge,head) in phase A (16 edges/pass), lanes=channels in phase B.
__global__ void gat_gather4(const __hip_bfloat16* __restrict__ h, const float* __restrict__ als,
                            const float* __restrict__ ald, const int* __restrict__ offs,
                            const int* __restrict__ csr, const float* __restrict__ bias,
                            float* __restrict__ pre, int N) {
  int wid = threadIdx.x >> 6, lane = threadIdx.x & 63;
  int n = blockIdx.x * 4 + wid;
  if (n >= N) return;
  __shared__ float lds_ex[4][64];  // [wid][e*4+t]
  __shared__ int lds_sn[4][16];

  int t = lane & 3;       // head (phase A)
  int e = lane >> 2;      // edge-in-tile 0..15 (phase A)
  int hh = lane >> 4;     // head (phase B, lane=channel)

  float aldt = ald[(long long)n * 4 + t];
  float exs = __expf(lrelu02(als[(long long)n * 4 + t] + aldt));  // self-loop
  float s = exs;
  float exsb = __shfl(exs, hh, 64);
  float acc = b2f(h[(long long)n * 64 + lane]) * exsb;
  int e0 = offs[n], e1 = offs[n + 1];

  for (int t0 = e0; t0 < e1; t0 += 16) {
    int idx = t0 + e;
    bool act = idx < e1;
    int sn = act ? csr[idx] : 0;
    float ex = act ? __expf(lrelu02(als[(long long)sn * 4 + t] + aldt)) : 0.f;
    float ts = ex;
#pragma unroll
    for (int ms = 4; ms < 64; ms <<= 1) ts += __shfl_xor(ts, ms, 64);
    s += ts;
    lds_ex[wid][lane] = ex;
    if (t == 0) lds_sn[wid][e] = sn;

    // Phase B: lanes = channels
    int cnt = e1 - t0; if (cnt > 16) cnt = 16;
#pragma unroll 4
    for (int j = 0; j < cnt; j++) {
      int sj = lds_sn[wid][j];
      acc += b2f(h[(long long)sj * 64 + lane]) * lds_ex[wid][(j << 2) + hh];
    }
  }
  float sb = __shfl(s, hh, 64);
  pre[(long long)n * 64 + lane] = acc / (sb + 1e-16f) + bias[lane];
}

// ---------------- Attention gather, H=1, no-max softmax: lanes=edges, 64/pass ----------------
__global__ void gat_gather1(const __hip_bfloat16* __restrict__ h, const float* __restrict__ als,
                            const float* __restrict__ ald, const int* __restrict__ offs,
                            const int* __restrict__ csr, const float* __restrict__ bias,
                            float* __restrict__ pre, int N) {
  int wid = threadIdx.x >> 6, lane = threadIdx.x & 63;
  int n = blockIdx.x * 4 + wid;
  if (n >= N) return;
  __shared__ float lds_ex[4][64];
  __shared__ int lds_sn[4][64];

  float aldn = ald[n];
  float exs = __expf(lrelu02(als[n] + aldn));
  float s = exs;
  float acc = b2f(h[(long long)n * 64 + lane]) * exs;
  int e0 = offs[n], e1 = offs[n + 1];

  for (int t0 = e0; t0 < e1; t0 += 64) {
    int idx = t0 + lane;
    bool act = idx < e1;
    int sn = act ? csr[idx] : 0;
    float ex = act ? __expf(lrelu02(als[sn] + aldn)) : 0.f;
    float ts = ex;
#pragma unroll
    for (int ms = 1; ms < 64; ms <<= 1) ts += __shfl_xor(ts, ms, 64);
    s += ts;
    lds_ex[wid][lane] = ex;
    lds_sn[wid][lane] = sn;

    int cnt = e1 - t0; if (cnt > 64) cnt = 64;
#pragma unroll 4
    for (int j = 0; j < cnt; j++) {
      int sj = lds_sn[wid][j];
      acc += b2f(h[(long long)sj * 64 + lane]) * lds_ex[wid][j];
    }
  }
  pre[(long long)n * 64 + lane] = acc / (s + 1e-16f) + bias[lane];
}

// ---------------- BatchNorm statistics ----------------
__global__ void bn_stats(const float* __restrict__ x, float* __restrict__ stats, int N) {
  int tid = threadIdx.x;
  int f = tid & 63;
  long long total = (long long)N * 64;
  long long stride = (long long)gridDim.x * THREADS;
  float s = 0.f, q = 0.f;
  for (long long i = (long long)blockIdx.x * THREADS + tid; i < total; i += stride) {
    float v = x[i];
    s += v;
    q += v * v;
  }
  __shared__ float ls[THREADS], lq[THREADS];
  ls[tid] = s;
  lq[tid] = q;
  __syncthreads();
  if (tid < 64) {
    s = ls[tid] + ls[tid + 64] + ls[tid + 128] + ls[tid + 192];
    q = lq[tid] + lq[tid + 64] + lq[tid + 128] + lq[tid + 192];
    atomicAdd(&stats[f], s);
    atomicAdd(&stats[64 + f], q);
  }
}

__global__ void bn_finalize(const float* __restrict__ stats, const float* __restrict__ g,
                            const float* __restrict__ be, float* __restrict__ ssc, int N) {
  int f = threadIdx.x;  // 64 threads
  float inv = 1.f / (float)N;
  float mu = stats[f] * inv;
  float var = stats[64 + f] * inv - mu * mu;
  float rstd = rsqrtf(var + 1e-5f);
  float sc = rstd * g[f];
  ssc[f] = sc;
  ssc[64 + f] = be[f] - mu * sc;
}

// ---------------- fused: nemb = elu(bn(pre3)); pool partial sums via per-wave run ----------------
__global__ void emb_pool_k(const float* __restrict__ pre, const float* __restrict__ ssc,
                           const int* __restrict__ batch, float* __restrict__ nemb,
                           float* __restrict__ pool, int N, int per) {
  int lane = threadIdx.x & 63, wid = threadIdx.x >> 6;
  int gw = blockIdx.x * 4 + wid;
  int n0 = gw * per;
  int n1 = n0 + per; if (n1 > N) n1 = N;
  if (n0 >= n1) return;
  float sc = ssc[lane], sh = ssc[64 + lane];
  float acc = 0.f;
  int cg = batch[n0];
  for (int n = n0; n < n1; n++) {
    int g = batch[n];
    if (g != cg) { atomicAdd(&pool[cg * 64 + lane], acc); acc = 0.f; cg = g; }
    float v = pre[(long long)n * 64 + lane] * sc + sh;
    v = v > 0.f ? v : (__expf(v) - 1.f);
    nemb[(long long)n * 64 + lane] = v;
    acc += v;
  }
  atomicAdd(&pool[cg * 64 + lane], acc);
}

// ---------------- classifier + embedding head, one block per graph ----------------
__global__ void head_k(const float* __restrict__ pool, const int* __restrict__ batch,
                       const float* __restrict__ Wc1, const float* __restrict__ bc1,
                       const float* __restrict__ Wc2, const float* __restrict__ bc2,
                       const float* __restrict__ We, const float* __restrict__ bee,
                       float* __restrict__ logits, float* __restrict__ emb, int N) {
  int g = blockIdx.x, lane = threadIdx.x;  // 64 threads
  __shared__ float pr[64], hid[32];
  __shared__ int bnds[2];
  if (lane < 2) {
    int target = g + lane;  // lower_bound(batch, target)
    int lo = 0, hi = N;
    while (lo < hi) {
      int mid = (lo + hi) >> 1;
      if (batch[mid] < target) lo = mid + 1; else hi = mid;
    }
    bnds[lane] = lo;
  }
  __syncthreads();
  float cnt = (float)(bnds[1] - bnds[0]);
  pr[lane] = pool[g * 64 + lane] / fmaxf(cnt, 1.f);
  __syncthreads();
  if (lane < 32) {
    float a = bc1[lane];
    for (int k = 0; k < 64; k++) a += pr[k] * Wc1[k * 32 + lane];
    hid[lane] = fmaxf(a, 0.f);
  }
  float e = bee[lane];
  for (int k = 0; k < 64; k++) e += pr[k] * We[k * 64 + lane];
  emb[g * 64 + lane] = e;
  __syncthreads();
  if (lane < 2) {
    float l = bc2[lane];
    for (int k = 0; k < 32; k++) l += hid[k] * Wc2[k * 2 + lane];
    logits[g * 2 + lane] = l;
  }
}

extern "C" void kernel_launch(void* const* d_in, const int* in_sizes, int n_in,
                              void* d_out, int out_size, void* d_ws, size_t ws_size,
                              hipStream_t stream) {
  const float* x    = (const float*)d_in[0];
  const int*   ei   = (const int*)d_in[1];
  const int*   batch= (const int*)d_in[2];
  const float* W1   = (const float*)d_in[3];
  const float* as1  = (const float*)d_in[4];
  const float* ad1  = (const float*)d_in[5];
  const float* b1   = (const float*)d_in[6];
  const float* g1   = (const float*)d_in[7];
  const float* be1  = (const float*)d_in[8];
  const float* W2   = (const float*)d_in[9];
  const float* as2  = (const float*)d_in[10];
  const float* ad2  = (const float*)d_in[11];
  const float* b2   = (const float*)d_in[12];
  const float* g2   = (const float*)d_in[13];
  const float* be2  = (const float*)d_in[14];
  const float* W3   = (const float*)d_in[15];
  const float* as3  = (const float*)d_in[16];
  const float* ad3  = (const float*)d_in[17];
  const float* b3   = (const float*)d_in[18];
  const float* g3   = (const float*)d_in[19];
  const float* be3  = (const float*)d_in[20];
  const float* Wc1  = (const float*)d_in[21];
  const float* bc1  = (const float*)d_in[22];
  const float* Wc2  = (const float*)d_in[23];
  const float* bc2  = (const float*)d_in[24];
  const float* We   = (const float*)d_in[25];
  const float* bee  = (const float*)d_in[26];

  int N = in_sizes[0] / 12;
  int E = in_sizes[1] / 2;
  const int* srcv = ei;
  const int* dstv = ei + E;

  char* p = (char*)d_ws;
  auto carve = [&](size_t bytes) -> char* {
    char* r = p;
    p += (bytes + 255) & ~(size_t)255;
    return r;
  };
  int* counts  = (int*)carve((size_t)N * 4);
  int* cursor  = (int*)carve((size_t)N * 4);
  int* offs    = (int*)carve((size_t)(N + 1) * 4);
  int* bsums   = (int*)carve(4096 * 4);
  int* csr     = (int*)carve((size_t)E * 4);
  __hip_bfloat16* h = (__hip_bfloat16*)carve((size_t)N * 64 * 2);
  float* als   = (float*)carve((size_t)N * 4 * 4);
  float* ald   = (float*)carve((size_t)N * 4 * 4);
  float* preA  = (float*)carve((size_t)N * 64 * 4);
  float* preB  = (float*)carve((size_t)N * 64 * 4);
  float* statsAll = (float*)carve(3 * 128 * 4);
  float* sscAll   = (float*)carve(3 * 128 * 4);
  float* poolbuf  = (float*)carve(64 * 64 * 4);

  hipMemsetAsync(counts, 0, (size_t)N * 4, stream);
  hipMemsetAsync(statsAll, 0, 3 * 128 * 4, stream);
  hipMemsetAsync(poolbuf, 0, 64 * 64 * 4, stream);

  int nbE = (E + THREADS - 1) / THREADS;
  int nbN = (N + THREADS - 1) / THREADS;
  int RS = (N + 7) / 8;  // dst-range size per XCD residue class
  hist_k<<<nbE, THREADS, 0, stream>>>(dstv, counts, E);
  scan1_k<<<nbN, THREADS, 0, stream>>>(counts, offs, bsums, N);
  scan2_k<<<1, 1024, 0, stream>>>(bsums, nbN);
  scan3_k<<<nbN, THREADS, 0, stream>>>(offs, cursor, bsums, N, E);
  scatter8_k<<<nbE * 8, THREADS, 0, stream>>>(srcv, dstv, cursor, csr, E, RS);

  int nbNode = (N + 3) / 4;
  // ---- layer 1 (K=12, H=4) ----
  gat_transform<12, false><<<nbNode, THREADS, 0, stream>>>(x, nullptr, W1, as1, ad1, h, als, ald, N, 4);
  gat_gather4<<<nbNode, THREADS, 0, stream>>>(h, als, ald, offs, csr, b1, preA, N);
  bn_stats<<<1024, THREADS, 0, stream>>>(preA, statsAll + 0, N);
  bn_finalize<<<1, 64, 0, stream>>>(statsAll + 0, g1, be1, sscAll + 0, N);
  // ---- layer 2 (K=64, H=4) ----
  gat_transform<64, true><<<nbNode, THREADS, 0, stream>>>(preA, sscAll + 0, W2, as2, ad2, h, als, ald, N, 4);
  gat_gather4<<<nbNode, THREADS, 0, stream>>>(h, als, ald, offs, csr, b2, preB, N);
  bn_stats<<<1024, THREADS, 0, stream>>>(preB, statsAll + 128, N);
  bn_finalize<<<1, 64, 0, stream>>>(statsAll + 128, g2, be2, sscAll + 128, N);
  // ---- layer 3 (K=64, H=1) ----
  gat_transform<64, true><<<nbNode, THREADS, 0, stream>>>(preB, sscAll + 128, W3, as3, ad3, h, als, ald, N, 1);
  gat_gather1<<<nbNode, THREADS, 0, stream>>>(h, als, ald, offs, csr, b3, preA, N);
  bn_stats<<<1024, THREADS, 0, stream>>>(preA, statsAll + 256, N);
  bn_finalize<<<1, 64, 0, stream>>>(statsAll + 256, g3, be3, sscAll + 256, N);

  float* outF   = (float*)d_out;
  float* logits = outF;
  float* emb    = outF + 64 * 2;
  float* nemb   = outF + 64 * 2 + 64 * 64;

  const int PER = 16;
  int nWaves = (N + PER - 1) / PER;
  int nbPool = (nWaves + 3) / 4;
  emb_pool_k<<<nbPool, THREADS, 0, stream>>>(preA, sscAll + 256, batch, nemb, poolbuf, N, PER);
  head_k<<<64, 64, 0, stream>>>(poolbuf, batch, Wc1, bc1, Wc2, bc2, We, bee, logits, emb, N);
}

// Round 7
// 497.946 us; speedup vs baseline: 2.5513x; 1.1122x over previous
//
#include <hip/hip_runtime.h>
#include <hip/hip_bf16.h>
#include <math.h>

#define THREADS 256

__device__ __forceinline__ float lrelu02(float x) { return x >= 0.f ? x : 0.2f * x; }
__device__ __forceinline__ float b2f(__hip_bfloat16 v) { return __bfloat162float(v); }

using bf16x8 = __attribute__((ext_vector_type(8))) short;
using f32x4  = __attribute__((ext_vector_type(4))) float;

// ---------------- CSR build ----------------
__global__ void hist_k(const int* __restrict__ dstv, int* __restrict__ counts, int E) {
  int i = blockIdx.x * THREADS + threadIdx.x;
  if (i < E) atomicAdd(&counts[dstv[i]], 1);
}

// XCD-partitioned scatter: blockIdx%8 ~ XCD id (round-robin dispatch heuristic);
// each residue class owns one dst range so csr/cursor lines stay in one L2.
__global__ void scatter8_k(const int* __restrict__ srcv, const int* __restrict__ dstv,
                           int* __restrict__ cursor, int* __restrict__ csr,
                           int E, int RS) {
  int s = blockIdx.x & 7;
  int i = (blockIdx.x >> 3) * THREADS + threadIdx.x;
  if (i >= E) return;
  int d = dstv[i];
  int lo = s * RS;
  if (d >= lo && d < lo + RS) {
    int p = atomicAdd(&cursor[d], 1);
    csr[p] = srcv[i];
  }
}

__global__ void scan1_k(const int* __restrict__ counts, int* __restrict__ offs,
                        int* __restrict__ bsums, int N) {
  __shared__ int s[THREADS];
  int i = blockIdx.x * THREADS + threadIdx.x;
  int v = (i < N) ? counts[i] : 0;
  s[threadIdx.x] = v;
  __syncthreads();
  for (int off = 1; off < THREADS; off <<= 1) {
    int t = (threadIdx.x >= off) ? s[threadIdx.x - off] : 0;
    __syncthreads();
    s[threadIdx.x] += t;
    __syncthreads();
  }
  if (i < N) offs[i] = s[threadIdx.x] - v;  // exclusive within block
  if (threadIdx.x == THREADS - 1) bsums[blockIdx.x] = s[THREADS - 1];
}

// parallel exclusive scan of block sums (nb <= 1024)
__global__ void scan2_k(int* bsums, int nb) {
  __shared__ int s[1024];
  int tid = threadIdx.x;
  int v = (tid < nb) ? bsums[tid] : 0;
  s[tid] = v;
  __syncthreads();
  for (int off = 1; off < 1024; off <<= 1) {
    int t = (tid >= off) ? s[tid - off] : 0;
    __syncthreads();
    s[tid] += t;
    __syncthreads();
  }
  if (tid < nb) bsums[tid] = s[tid] - v;
}

__global__ void scan3_k(int* offs, int* __restrict__ cursor,
                        const int* __restrict__ bsums, int N, int E) {
  int i = blockIdx.x * THREADS + threadIdx.x;
  if (i < N) {
    int v = offs[i] + bsums[blockIdx.x];
    offs[i] = v;
    cursor[i] = v;  // scatter cursor starts at row offset
  }
  if (i == 0) offs[N] = E;
}

// ---------------- W transpose + bf16 cast (one-time, tiny) ----------------
__global__ void wprep_k(const float* __restrict__ W2, const float* __restrict__ W3,
                        __hip_bfloat16* __restrict__ wt2, __hip_bfloat16* __restrict__ wt3) {
  const float* W = blockIdx.x ? W3 : W2;
  __hip_bfloat16* o = blockIdx.x ? wt3 : wt2;
  for (int i = threadIdx.x; i < 4096; i += THREADS) {
    int n = i >> 6, k = i & 63;
    o[n * 64 + k] = __float2bfloat16(W[k * 64 + n]);  // WT[n][k] = W[k][n]
  }
}

// ---------------- fused BN + ELU + bf16 cast: xb = bf16(elu(bn(pre))) ----------------
__global__ void act_cast_k(const float* __restrict__ pre, const float* __restrict__ ssc,
                           __hip_bfloat16* __restrict__ xb, long long total) {
  long long i = ((long long)blockIdx.x * THREADS + threadIdx.x) * 4;
  if (i >= total) return;
  float4 v = *(const float4*)(pre + i);
  int c = (int)(i & 63);
  float r0 = v.x * ssc[c] + ssc[64 + c];
  float r1 = v.y * ssc[c + 1] + ssc[64 + c + 1];
  float r2 = v.z * ssc[c + 2] + ssc[64 + c + 2];
  float r3 = v.w * ssc[c + 3] + ssc[64 + c + 3];
  r0 = r0 > 0.f ? r0 : (__expf(r0) - 1.f);
  r1 = r1 > 0.f ? r1 : (__expf(r1) - 1.f);
  r2 = r2 > 0.f ? r2 : (__expf(r2) - 1.f);
  r3 = r3 > 0.f ? r3 : (__expf(r3) - 1.f);
  xb[i]     = __float2bfloat16(r0);
  xb[i + 1] = __float2bfloat16(r1);
  xb[i + 2] = __float2bfloat16(r2);
  xb[i + 3] = __float2bfloat16(r3);
}

// ---------------- MFMA transform: h = xb @ W (K=64), + attention dots ----------------
// Block = 4 waves x 16 nodes. A-frag: row=lane&15, k=(lane>>4)*8+i (contiguous from xb).
// B-frag from WT[n][k] (transposed W): col=lane&15, same k slice. D: col=lane&15,
// row=(lane>>4)*4+j. Head t = subtile s for H=4 (16 ch/head aligns with subtile).
template <int H>
__global__ __launch_bounds__(256) void transform_mfma(
    const __hip_bfloat16* __restrict__ xb, const __hip_bfloat16* __restrict__ wt,
    const float* __restrict__ aS, const float* __restrict__ aD,
    __hip_bfloat16* __restrict__ h, float* __restrict__ als, float* __restrict__ ald,
    int N) {
  int wid = threadIdx.x >> 6, lane = threadIdx.x & 63;
  int m0 = blockIdx.x * 64 + wid * 16;
  int r = lane & 15, g = lane >> 4;
  const bf16x8* arow = (const bf16x8*)(xb + (long long)(m0 + r) * 64 + g * 8);
  bf16x8 a0 = arow[0];
  bf16x8 a1 = arow[4];  // +32 bf16
  f32x4 acc[4];
#pragma unroll
  for (int s = 0; s < 4; s++) acc[s] = (f32x4){0.f, 0.f, 0.f, 0.f};
#pragma unroll
  for (int s = 0; s < 4; s++) {
    const bf16x8* brow = (const bf16x8*)(wt + (s * 16 + r) * 64 + g * 8);
    acc[s] = __builtin_amdgcn_mfma_f32_16x16x32_bf16(a0, brow[0], acc[s], 0, 0, 0);
    acc[s] = __builtin_amdgcn_mfma_f32_16x16x32_bf16(a1, brow[4], acc[s], 0, 0, 0);
  }
  float asum[4] = {0.f, 0.f, 0.f, 0.f}, dsum[4] = {0.f, 0.f, 0.f, 0.f};
#pragma unroll
  for (int s = 0; s < 4; s++) {
    int n = s * 16 + r;
    float sv = aS[n], dv = aD[n];
    float ts[4], td[4];
#pragma unroll
    for (int j = 0; j < 4; j++) { ts[j] = acc[s][j] * sv; td[j] = acc[s][j] * dv; }
#pragma unroll
    for (int mk = 1; mk < 16; mk <<= 1) {
#pragma unroll
      for (int j = 0; j < 4; j++) {
        ts[j] += __shfl_xor(ts[j], mk, 64);
        td[j] += __shfl_xor(td[j], mk, 64);
      }
    }
#pragma unroll
    for (int j = 0; j < 4; j++) {
      int m = m0 + g * 4 + j;
      if (m < N) {
        h[(long long)m * 64 + n] = __float2bfloat16(acc[s][j]);
        if (H == 4) {
          if (r == 0) { als[m * 4 + s] = ts[j]; ald[m * 4 + s] = td[j]; }
        }
      }
      if (H == 1) { asum[j] += ts[j]; dsum[j] += td[j]; }
    }
  }
  if (H == 1 && r == 0) {
#pragma unroll
    for (int j = 0; j < 4; j++) {
      int m = m0 + g * 4 + j;
      if (m < N) { als[m] = asum[j]; ald[m] = dsum[j]; }
    }
  }
}

// ---------------- layer-1 scalar transform (K=12) ----------------
template <int K>
__global__ void gat_transform(const float* __restrict__ xin,
                              const float* __restrict__ W, const float* __restrict__ aS,
                              const float* __restrict__ aD, __hip_bfloat16* __restrict__ h,
                              float* __restrict__ als, float* __restrict__ ald,
                              int N, int H) {
  int wave = threadIdx.x >> 6;
  int lane = threadIdx.x & 63;
  int n = blockIdx.x * 4 + wave;
  __shared__ float xs[4][K];
  if (n < N && lane < K) xs[wave][lane] = xin[(long long)n * K + lane];
  __syncthreads();
  if (n >= N) return;
  float acc = 0.f;
#pragma unroll
  for (int k = 0; k < K; k++) acc += xs[wave][k] * W[k * 64 + lane];
  h[(long long)n * 64 + lane] = __float2bfloat16(acc);
  int C = 64 / H;
  float ts = acc * aS[lane], td = acc * aD[lane];
  for (int m = 1; m < C; m <<= 1) {
    ts += __shfl_xor(ts, m, 64);
    td += __shfl_xor(td, m, 64);
  }
  if ((lane & (C - 1)) == 0) {
    int hh = lane / C;
    als[(long long)n * H + hh] = ts;
    ald[(long long)n * H + hh] = td;
  }
}

// ---------------- Attention gather, H=4, no-max softmax (logits provably tiny) ----------------
__global__ void gat_gather4(const __hip_bfloat16* __restrict__ h, const float* __restrict__ als,
                            const float* __restrict__ ald, const int* __restrict__ offs,
                            const int* __restrict__ csr, const float* __restrict__ bias,
                            float* __restrict__ pre, int N) {
  int wid = threadIdx.x >> 6, lane = threadIdx.x & 63;
  int n = blockIdx.x * 4 + wid;
  if (n >= N) return;
  __shared__ float lds_ex[4][64];  // [wid][e*4+t]
  __shared__ int lds_sn[4][16];

  int t = lane & 3;       // head (phase A)
  int e = lane >> 2;      // edge-in-tile 0..15 (phase A)
  int hh = lane >> 4;     // head (phase B, lane=channel)

  float aldt = ald[(long long)n * 4 + t];
  float exs = __expf(lrelu02(als[(long long)n * 4 + t] + aldt));  // self-loop
  float s = exs;
  float exsb = __shfl(exs, hh, 64);
  float acc = b2f(h[(long long)n * 64 + lane]) * exsb;
  int e0 = offs[n], e1 = offs[n + 1];

  for (int t0 = e0; t0 < e1; t0 += 16) {
    int idx = t0 + e;
    bool act = idx < e1;
    int sn = act ? csr[idx] : 0;
    float ex = act ? __expf(lrelu02(als[(long long)sn * 4 + t] + aldt)) : 0.f;
    float ts = ex;
#pragma unroll
    for (int ms = 4; ms < 64; ms <<= 1) ts += __shfl_xor(ts, ms, 64);
    s += ts;
    lds_ex[wid][lane] = ex;
    if (t == 0) lds_sn[wid][e] = sn;

    int cnt = e1 - t0; if (cnt > 16) cnt = 16;
#pragma unroll 4
    for (int j = 0; j < cnt; j++) {
      int sj = lds_sn[wid][j];
      acc += b2f(h[(long long)sj * 64 + lane]) * lds_ex[wid][(j << 2) + hh];
    }
  }
  float sb = __shfl(s, hh, 64);
  pre[(long long)n * 64 + lane] = acc / (sb + 1e-16f) + bias[lane];
}

// ---------------- Attention gather, H=1, no-max softmax: lanes=edges, 64/pass ----------------
__global__ void gat_gather1(const __hip_bfloat16* __restrict__ h, const float* __restrict__ als,
                            const float* __restrict__ ald, const int* __restrict__ offs,
                            const int* __restrict__ csr, const float* __restrict__ bias,
                            float* __restrict__ pre, int N) {
  int wid = threadIdx.x >> 6, lane = threadIdx.x & 63;
  int n = blockIdx.x * 4 + wid;
  if (n >= N) return;
  __shared__ float lds_ex[4][64];
  __shared__ int lds_sn[4][64];

  float aldn = ald[n];
  float exs = __expf(lrelu02(als[n] + aldn));
  float s = exs;
  float acc = b2f(h[(long long)n * 64 + lane]) * exs;
  int e0 = offs[n], e1 = offs[n + 1];

  for (int t0 = e0; t0 < e1; t0 += 64) {
    int idx = t0 + lane;
    bool act = idx < e1;
    int sn = act ? csr[idx] : 0;
    float ex = act ? __expf(lrelu02(als[sn] + aldn)) : 0.f;
    float ts = ex;
#pragma unroll
    for (int ms = 1; ms < 64; ms <<= 1) ts += __shfl_xor(ts, ms, 64);
    s += ts;
    lds_ex[wid][lane] = ex;
    lds_sn[wid][lane] = sn;

    int cnt = e1 - t0; if (cnt > 64) cnt = 64;
#pragma unroll 4
    for (int j = 0; j < cnt; j++) {
      int sj = lds_sn[wid][j];
      acc += b2f(h[(long long)sj * 64 + lane]) * lds_ex[wid][j];
    }
  }
  pre[(long long)n * 64 + lane] = acc / (s + 1e-16f) + bias[lane];
}

// ---------------- BatchNorm statistics ----------------
__global__ void bn_stats(const float* __restrict__ x, float* __restrict__ stats, int N) {
  int tid = threadIdx.x;
  int f = tid & 63;
  long long total = (long long)N * 64;
  long long stride = (long long)gridDim.x * THREADS;
  float s = 0.f, q = 0.f;
  for (long long i = (long long)blockIdx.x * THREADS + tid; i < total; i += stride) {
    float v = x[i];
    s += v;
    q += v * v;
  }
  __shared__ float ls[THREADS], lq[THREADS];
  ls[tid] = s;
  lq[tid] = q;
  __syncthreads();
  if (tid < 64) {
    s = ls[tid] + ls[tid + 64] + ls[tid + 128] + ls[tid + 192];
    q = lq[tid] + lq[tid + 64] + lq[tid + 128] + lq[tid + 192];
    atomicAdd(&stats[f], s);
    atomicAdd(&stats[64 + f], q);
  }
}

__global__ void bn_finalize(const float* __restrict__ stats, const float* __restrict__ g,
                            const float* __restrict__ be, float* __restrict__ ssc, int N) {
  int f = threadIdx.x;  // 64 threads
  float inv = 1.f / (float)N;
  float mu = stats[f] * inv;
  float var = stats[64 + f] * inv - mu * mu;
  float rstd = rsqrtf(var + 1e-5f);
  float sc = rstd * g[f];
  ssc[f] = sc;
  ssc[64 + f] = be[f] - mu * sc;
}

// ---------------- fused: nemb = elu(bn(pre3)); pool partial sums via per-wave run ----------------
__global__ void emb_pool_k(const float* __restrict__ pre, const float* __restrict__ ssc,
                           const int* __restrict__ batch, float* __restrict__ nemb,
                           float* __restrict__ pool, int N, int per) {
  int lane = threadIdx.x & 63, wid = threadIdx.x >> 6;
  int gw = blockIdx.x * 4 + wid;
  int n0 = gw * per;
  int n1 = n0 + per; if (n1 > N) n1 = N;
  if (n0 >= n1) return;
  float sc = ssc[lane], sh = ssc[64 + lane];
  float acc = 0.f;
  int cg = batch[n0];
  for (int n = n0; n < n1; n++) {
    int g = batch[n];
    if (g != cg) { atomicAdd(&pool[cg * 64 + lane], acc); acc = 0.f; cg = g; }
    float v = pre[(long long)n * 64 + lane] * sc + sh;
    v = v > 0.f ? v : (__expf(v) - 1.f);
    nemb[(long long)n * 64 + lane] = v;
    acc += v;
  }
  atomicAdd(&pool[cg * 64 + lane], acc);
}

// ---------------- classifier + embedding head, one block per graph ----------------
__global__ void head_k(const float* __restrict__ pool, const int* __restrict__ batch,
                       const float* __restrict__ Wc1, const float* __restrict__ bc1,
                       const float* __restrict__ Wc2, const float* __restrict__ bc2,
                       const float* __restrict__ We, const float* __restrict__ bee,
                       float* __restrict__ logits, float* __restrict__ emb, int N) {
  int g = blockIdx.x, lane = threadIdx.x;  // 64 threads
  __shared__ float pr[64], hid[32];
  __shared__ int bnds[2];
  if (lane < 2) {
    int target = g + lane;  // lower_bound(batch, target)
    int lo = 0, hi = N;
    while (lo < hi) {
      int mid = (lo + hi) >> 1;
      if (batch[mid] < target) lo = mid + 1; else hi = mid;
    }
    bnds[lane] = lo;
  }
  __syncthreads();
  float cnt = (float)(bnds[1] - bnds[0]);
  pr[lane] = pool[g * 64 + lane] / fmaxf(cnt, 1.f);
  __syncthreads();
  if (lane < 32) {
    float a = bc1[lane];
    for (int k = 0; k < 64; k++) a += pr[k] * Wc1[k * 32 + lane];
    hid[lane] = fmaxf(a, 0.f);
  }
  float e = bee[lane];
  for (int k = 0; k < 64; k++) e += pr[k] * We[k * 64 + lane];
  emb[g * 64 + lane] = e;
  __syncthreads();
  if (lane < 2) {
    float l = bc2[lane];
    for (int k = 0; k < 32; k++) l += hid[k] * Wc2[k * 2 + lane];
    logits[g * 2 + lane] = l;
  }
}

extern "C" void kernel_launch(void* const* d_in, const int* in_sizes, int n_in,
                              void* d_out, int out_size, void* d_ws, size_t ws_size,
                              hipStream_t stream) {
  const float* x    = (const float*)d_in[0];
  const int*   ei   = (const int*)d_in[1];
  const int*   batch= (const int*)d_in[2];
  const float* W1   = (const float*)d_in[3];
  const float* as1  = (const float*)d_in[4];
  const float* ad1  = (const float*)d_in[5];
  const float* b1   = (const float*)d_in[6];
  const float* g1   = (const float*)d_in[7];
  const float* be1  = (const float*)d_in[8];
  const float* W2   = (const float*)d_in[9];
  const float* as2  = (const float*)d_in[10];
  const float* ad2  = (const float*)d_in[11];
  const float* b2   = (const float*)d_in[12];
  const float* g2   = (const float*)d_in[13];
  const float* be2  = (const float*)d_in[14];
  const float* W3   = (const float*)d_in[15];
  const float* as3  = (const float*)d_in[16];
  const float* ad3  = (const float*)d_in[17];
  const float* b3   = (const float*)d_in[18];
  const float* g3   = (const float*)d_in[19];
  const float* be3  = (const float*)d_in[20];
  const float* Wc1  = (const float*)d_in[21];
  const float* bc1  = (const float*)d_in[22];
  const float* Wc2  = (const float*)d_in[23];
  const float* bc2  = (const float*)d_in[24];
  const float* We   = (const float*)d_in[25];
  const float* bee  = (const float*)d_in[26];

  int N = in_sizes[0] / 12;
  int E = in_sizes[1] / 2;
  const int* srcv = ei;
  const int* dstv = ei + E;

  char* p = (char*)d_ws;
  auto carve = [&](size_t bytes) -> char* {
    char* r = p;
    p += (bytes + 255) & ~(size_t)255;
    return r;
  };
  int* counts  = (int*)carve((size_t)N * 4);
  int* cursor  = (int*)carve((size_t)N * 4);
  int* offs    = (int*)carve((size_t)(N + 1) * 4);
  int* bsums   = (int*)carve(4096 * 4);
  int* csr     = (int*)carve((size_t)E * 4);
  __hip_bfloat16* h  = (__hip_bfloat16*)carve((size_t)N * 64 * 2);
  __hip_bfloat16* xb = (__hip_bfloat16*)carve((size_t)(N + 64) * 64 * 2);
  __hip_bfloat16* wt2 = (__hip_bfloat16*)carve(64 * 64 * 2);
  __hip_bfloat16* wt3 = (__hip_bfloat16*)carve(64 * 64 * 2);
  float* als   = (float*)carve((size_t)N * 4 * 4);
  float* ald   = (float*)carve((size_t)N * 4 * 4);
  float* preA  = (float*)carve((size_t)N * 64 * 4);
  float* preB  = (float*)carve((size_t)N * 64 * 4);
  float* statsAll = (float*)carve(3 * 128 * 4);
  float* sscAll   = (float*)carve(3 * 128 * 4);
  float* poolbuf  = (float*)carve(64 * 64 * 4);

  hipMemsetAsync(counts, 0, (size_t)N * 4, stream);
  hipMemsetAsync(statsAll, 0, 3 * 128 * 4, stream);
  hipMemsetAsync(poolbuf, 0, 64 * 64 * 4, stream);

  int nbE = (E + THREADS - 1) / THREADS;
  int nbN = (N + THREADS - 1) / THREADS;
  int RS = (N + 7) / 8;  // dst-range size per XCD residue class
  wprep_k<<<2, THREADS, 0, stream>>>(W2, W3, wt2, wt3);
  hist_k<<<nbE, THREADS, 0, stream>>>(dstv, counts, E);
  scan1_k<<<nbN, THREADS, 0, stream>>>(counts, offs, bsums, N);
  scan2_k<<<1, 1024, 0, stream>>>(bsums, nbN);
  scan3_k<<<nbN, THREADS, 0, stream>>>(offs, cursor, bsums, N, E);
  scatter8_k<<<nbE * 8, THREADS, 0, stream>>>(srcv, dstv, cursor, csr, E, RS);

  int nbNode = (N + 3) / 4;
  int nbT = (N + 63) / 64;
  long long tot64 = (long long)N * 64;
  int nbC = (int)((tot64 / 4 + THREADS - 1) / THREADS);

  // ---- layer 1 (K=12, H=4, scalar) ----
  gat_transform<12><<<nbNode, THREADS, 0, stream>>>(x, W1, as1, ad1, h, als, ald, N, 4);
  gat_gather4<<<nbNode, THREADS, 0, stream>>>(h, als, ald, offs, csr, b1, preA, N);
  bn_stats<<<1024, THREADS, 0, stream>>>(preA, statsAll + 0, N);
  bn_finalize<<<1, 64, 0, stream>>>(statsAll + 0, g1, be1, sscAll + 0, N);
  // ---- layer 2 (K=64, H=4, MFMA) ----
  act_cast_k<<<nbC, THREADS, 0, stream>>>(preA, sscAll + 0, xb, tot64);
  transform_mfma<4><<<nbT, THREADS, 0, stream>>>(xb, wt2, as2, ad2, h, als, ald, N);
  gat_gather4<<<nbNode, THREADS, 0, stream>>>(h, als, ald, offs, csr, b2, preB, N);
  bn_stats<<<1024, THREADS, 0, stream>>>(preB, statsAll + 128, N);
  bn_finalize<<<1, 64, 0, stream>>>(statsAll + 128, g2, be2, sscAll + 128, N);
  // ---- layer 3 (K=64, H=1, MFMA) ----
  act_cast_k<<<nbC, THREADS, 0, stream>>>(preB, sscAll + 128, xb, tot64);
  transform_mfma<1><<<nbT, THREADS, 0, stream>>>(xb, wt3, as3, ad3, h, als, ald, N);
  gat_gather1<<<nbNode, THREADS, 0, stream>>>(h, als, ald, offs, csr, b3, preA, N);
  bn_stats<<<1024, THREADS, 0, stream>>>(preA, statsAll + 256, N);
  bn_finalize<<<1, 64, 0, stream>>>(statsAll + 256, g3, be3, sscAll + 256, N);

  float* outF   = (float*)d_out;
  float* logits = outF;
  float* emb    = outF + 64 * 2;
  float* nemb   = outF + 64 * 2 + 64 * 64;

  const int PER = 16;
  int nWaves = (N + PER - 1) / PER;
  int nbPool = (nWaves + 3) / 4;
  emb_pool_k<<<nbPool, THREADS, 0, stream>>>(preA, sscAll + 256, batch, nemb, poolbuf, N, PER);
  head_k<<<64, 64, 0, stream>>>(poolbuf, batch, Wc1, bc1, Wc2, bc2, We, bee, logits, emb, N);
}

// Round 8
// 459.823 us; speedup vs baseline: 2.7628x; 1.0829x over previous
//
#include <hip/hip_runtime.h>
#include <hip/hip_bf16.h>
#include <math.h>

#define THREADS 256

__device__ __forceinline__ float lrelu02(float x) { return x >= 0.f ? x : 0.2f * x; }
__device__ __forceinline__ float b2f(__hip_bfloat16 v) { return __bfloat162float(v); }
__device__ __forceinline__ short f2bf_bits(float v) {
  __hip_bfloat16 hb = __float2bfloat16(v);
  return *reinterpret_cast<short*>(&hb);
}

using bf16x8 = __attribute__((ext_vector_type(8))) short;
using f32x4  = __attribute__((ext_vector_type(4))) float;

// ---------------- CSR build ----------------
__global__ void hist_k(const int* __restrict__ dstv, int* __restrict__ counts, int E) {
  int i = blockIdx.x * THREADS + threadIdx.x;
  if (i < E) atomicAdd(&counts[dstv[i]], 1);
}

// XCD-partitioned scatter: blockIdx%8 ~ XCD id (round-robin dispatch heuristic);
// each residue class owns one dst range so csr/cursor lines stay in one L2.
__global__ void scatter8_k(const int* __restrict__ srcv, const int* __restrict__ dstv,
                           int* __restrict__ cursor, int* __restrict__ csr,
                           int E, int RS) {
  int s = blockIdx.x & 7;
  int i = (blockIdx.x >> 3) * THREADS + threadIdx.x;
  if (i >= E) return;
  int d = dstv[i];
  int lo = s * RS;
  if (d >= lo && d < lo + RS) {
    int p = atomicAdd(&cursor[d], 1);
    csr[p] = srcv[i];
  }
}

__global__ void scan1_k(const int* __restrict__ counts, int* __restrict__ offs,
                        int* __restrict__ bsums, int N) {
  __shared__ int s[THREADS];
  int i = blockIdx.x * THREADS + threadIdx.x;
  int v = (i < N) ? counts[i] : 0;
  s[threadIdx.x] = v;
  __syncthreads();
  for (int off = 1; off < THREADS; off <<= 1) {
    int t = (threadIdx.x >= off) ? s[threadIdx.x - off] : 0;
    __syncthreads();
    s[threadIdx.x] += t;
    __syncthreads();
  }
  if (i < N) offs[i] = s[threadIdx.x] - v;  // exclusive within block
  if (threadIdx.x == THREADS - 1) bsums[blockIdx.x] = s[THREADS - 1];
}

// parallel exclusive scan of block sums (nb <= 1024)
__global__ void scan2_k(int* bsums, int nb) {
  __shared__ int s[1024];
  int tid = threadIdx.x;
  int v = (tid < nb) ? bsums[tid] : 0;
  s[tid] = v;
  __syncthreads();
  for (int off = 1; off < 1024; off <<= 1) {
    int t = (tid >= off) ? s[tid - off] : 0;
    __syncthreads();
    s[tid] += t;
    __syncthreads();
  }
  if (tid < nb) bsums[tid] = s[tid] - v;
}

__global__ void scan3_k(int* offs, int* __restrict__ cursor,
                        const int* __restrict__ bsums, int N, int E) {
  int i = blockIdx.x * THREADS + threadIdx.x;
  if (i < N) {
    int v = offs[i] + bsums[blockIdx.x];
    offs[i] = v;
    cursor[i] = v;  // scatter cursor starts at row offset
  }
  if (i == 0) offs[N] = E;
}

// ---------------- W transpose + bf16 cast (one-time, tiny) ----------------
__global__ void wprep_k(const float* __restrict__ W2, const float* __restrict__ W3,
                        __hip_bfloat16* __restrict__ wt2, __hip_bfloat16* __restrict__ wt3) {
  const float* W = blockIdx.x ? W3 : W2;
  __hip_bfloat16* o = blockIdx.x ? wt3 : wt2;
  for (int i = threadIdx.x; i < 4096; i += THREADS) {
    int n = i >> 6, k = i & 63;
    o[n * 64 + k] = __float2bfloat16(W[k * 64 + n]);  // WT[n][k] = W[k][n]
  }
}

// ---------------- MFMA transform, fused BN+ELU+cast: h = elu(bn(pre)) @ W ----------------
// Block = 4 waves x 16 nodes. A-frag built in-register from f32 pre + ssc.
// B-frag from WT[n][k]: col=lane&15, k-slice=(lane>>4)*8. D: col=lane&15, row=g*4+j.
template <int H>
__global__ __launch_bounds__(256) void transform_mfma(
    const float* __restrict__ pre, const float* __restrict__ ssc,
    const __hip_bfloat16* __restrict__ wt,
    const float* __restrict__ aS, const float* __restrict__ aD,
    __hip_bfloat16* __restrict__ h, float* __restrict__ als, float* __restrict__ ald,
    int N) {
  int wid = threadIdx.x >> 6, lane = threadIdx.x & 63;
  int m0 = blockIdx.x * 64 + wid * 16;
  int r = lane & 15, g = lane >> 4;
  const float* arow = pre + (long long)(m0 + r) * 64;
  int k0 = g * 8;
  bf16x8 a0, a1;
#pragma unroll
  for (int i = 0; i < 8; i++) {
    int ka = k0 + i, kb = k0 + 32 + i;
    float va = arow[ka] * ssc[ka] + ssc[64 + ka];
    float vb = arow[kb] * ssc[kb] + ssc[64 + kb];
    va = va > 0.f ? va : (__expf(va) - 1.f);
    vb = vb > 0.f ? vb : (__expf(vb) - 1.f);
    a0[i] = f2bf_bits(va);
    a1[i] = f2bf_bits(vb);
  }
  f32x4 acc[4];
#pragma unroll
  for (int s = 0; s < 4; s++) acc[s] = (f32x4){0.f, 0.f, 0.f, 0.f};
#pragma unroll
  for (int s = 0; s < 4; s++) {
    const bf16x8* brow = (const bf16x8*)(wt + (s * 16 + r) * 64 + k0);
    acc[s] = __builtin_amdgcn_mfma_f32_16x16x32_bf16(a0, brow[0], acc[s], 0, 0, 0);
    acc[s] = __builtin_amdgcn_mfma_f32_16x16x32_bf16(a1, brow[4], acc[s], 0, 0, 0);
  }
  float asum[4] = {0.f, 0.f, 0.f, 0.f}, dsum[4] = {0.f, 0.f, 0.f, 0.f};
#pragma unroll
  for (int s = 0; s < 4; s++) {
    int n = s * 16 + r;
    float sv = aS[n], dv = aD[n];
    float ts[4], td[4];
#pragma unroll
    for (int j = 0; j < 4; j++) { ts[j] = acc[s][j] * sv; td[j] = acc[s][j] * dv; }
#pragma unroll
    for (int mk = 1; mk < 16; mk <<= 1) {
#pragma unroll
      for (int j = 0; j < 4; j++) {
        ts[j] += __shfl_xor(ts[j], mk, 64);
        td[j] += __shfl_xor(td[j], mk, 64);
      }
    }
#pragma unroll
    for (int j = 0; j < 4; j++) {
      int m = m0 + g * 4 + j;
      if (m < N) {
        h[(long long)m * 64 + n] = __float2bfloat16(acc[s][j]);
        if (H == 4) {
          if (r == 0) { als[m * 4 + s] = ts[j]; ald[m * 4 + s] = td[j]; }
        }
      }
      if (H == 1) { asum[j] += ts[j]; dsum[j] += td[j]; }
    }
  }
  if (H == 1 && r == 0) {
#pragma unroll
    for (int j = 0; j < 4; j++) {
      int m = m0 + g * 4 + j;
      if (m < N) { als[m] = asum[j]; ald[m] = dsum[j]; }
    }
  }
}

// ---------------- layer-1 scalar transform (K=12) ----------------
template <int K>
__global__ void gat_transform(const float* __restrict__ xin,
                              const float* __restrict__ W, const float* __restrict__ aS,
                              const float* __restrict__ aD, __hip_bfloat16* __restrict__ h,
                              float* __restrict__ als, float* __restrict__ ald,
                              int N, int H) {
  int wave = threadIdx.x >> 6;
  int lane = threadIdx.x & 63;
  int n = blockIdx.x * 4 + wave;
  __shared__ float xs[4][K];
  if (n < N && lane < K) xs[wave][lane] = xin[(long long)n * K + lane];
  __syncthreads();
  if (n >= N) return;
  float acc = 0.f;
#pragma unroll
  for (int k = 0; k < K; k++) acc += xs[wave][k] * W[k * 64 + lane];
  h[(long long)n * 64 + lane] = __float2bfloat16(acc);
  int C = 64 / H;
  float ts = acc * aS[lane], td = acc * aD[lane];
  for (int m = 1; m < C; m <<= 1) {
    ts += __shfl_xor(ts, m, 64);
    td += __shfl_xor(td, m, 64);
  }
  if ((lane & (C - 1)) == 0) {
    int hh = lane / C;
    als[(long long)n * H + hh] = ts;
    ald[(long long)n * H + hh] = td;
  }
}

// ---------------- Attention gather, H=4, LDS-free ----------------
// Phase A: lanes=(edge,head), 16 edges/pass. Phase B: sn broadcast via const-index
// readlane (scalar-base h loads), ex via ds_bpermute; s reduced once at the end.
__global__ void gat_gather4(const __hip_bfloat16* __restrict__ h, const float* __restrict__ als,
                            const float* __restrict__ ald, const int* __restrict__ offs,
                            const int* __restrict__ csr, const float* __restrict__ bias,
                            float* __restrict__ pre, int N) {
  int wid = threadIdx.x >> 6, lane = threadIdx.x & 63;
  int n = blockIdx.x * 4 + wid;
  if (n >= N) return;
  int t = lane & 3;       // head (phase A)
  int e = lane >> 2;      // edge-in-tile (phase A)
  int hh = lane >> 4;     // head (phase B, lane=channel)

  float aldt = ald[n * 4 + t];
  float exs = __expf(lrelu02(als[n * 4 + t] + aldt));  // self-loop
  float sacc = 0.f;
  float acc = 0.f;
  int e0 = offs[n], e1 = offs[n + 1];

  for (int t0 = e0; t0 < e1; t0 += 16) {
    int idx = t0 + e;
    bool act = idx < e1;
    int sn = act ? csr[idx] : 0;
    float ex = act ? __expf(lrelu02(als[sn * 4 + t] + aldt)) : 0.f;
    sacc += ex;
#pragma unroll
    for (int j = 0; j < 16; j++) {
      int sj = __builtin_amdgcn_readlane(sn, j << 2);       // wave-uniform -> SGPR
      float exj = __shfl(ex, (j << 2) + hh, 64);            // bpermute
      acc += b2f(h[(long long)sj * 64 + lane]) * exj;
    }
  }
#pragma unroll
  for (int ms = 4; ms < 64; ms <<= 1) sacc += __shfl_xor(sacc, ms, 64);
  float s = sacc + exs;
  float exsb = __shfl(exs, hh, 64);
  float sb = __shfl(s, hh, 64);
  acc += b2f(h[(long long)n * 64 + lane]) * exsb;
  pre[(long long)n * 64 + lane] = acc / (sb + 1e-16f) + bias[lane];
}

// ---------------- Attention gather, H=1, LDS-free: lanes=edges, 64/pass ----------------
__global__ void gat_gather1(const __hip_bfloat16* __restrict__ h, const float* __restrict__ als,
                            const float* __restrict__ ald, const int* __restrict__ offs,
                            const int* __restrict__ csr, const float* __restrict__ bias,
                            float* __restrict__ pre, int N) {
  int wid = threadIdx.x >> 6, lane = threadIdx.x & 63;
  int n = blockIdx.x * 4 + wid;
  if (n >= N) return;

  float aldn = ald[n];
  float exs = __expf(lrelu02(als[n] + aldn));
  float sacc = 0.f, acc = 0.f;
  int e0 = offs[n], e1 = offs[n + 1];

  for (int t0 = e0; t0 < e1; t0 += 64) {
    int idx = t0 + lane;
    bool act = idx < e1;
    int sn = act ? csr[idx] : 0;
    float ex = act ? __expf(lrelu02(als[sn] + aldn)) : 0.f;
    sacc += ex;
    int cnt = e1 - t0;
#pragma unroll
    for (int c = 0; c < 4; c++) {
      if (c * 16 >= cnt) break;  // wave-uniform
#pragma unroll
      for (int j = 0; j < 16; j++) {
        int ln = c * 16 + j;
        int sj = __builtin_amdgcn_readlane(sn, ln);
        float exj = __int_as_float(__builtin_amdgcn_readlane(__float_as_int(ex), ln));
        acc += b2f(h[(long long)sj * 64 + lane]) * exj;
      }
    }
  }
#pragma unroll
  for (int ms = 1; ms < 64; ms <<= 1) sacc += __shfl_xor(sacc, ms, 64);
  float s = sacc + exs;
  acc += b2f(h[(long long)n * 64 + lane]) * exs;
  pre[(long long)n * 64 + lane] = acc / (s + 1e-16f) + bias[lane];
}

// ---------------- BatchNorm statistics ----------------
__global__ void bn_stats(const float* __restrict__ x, float* __restrict__ stats, int N) {
  int tid = threadIdx.x;
  int f = tid & 63;
  long long total = (long long)N * 64;
  long long stride = (long long)gridDim.x * THREADS;
  float s = 0.f, q = 0.f;
  for (long long i = (long long)blockIdx.x * THREADS + tid; i < total; i += stride) {
    float v = x[i];
    s += v;
    q += v * v;
  }
  __shared__ float ls[THREADS], lq[THREADS];
  ls[tid] = s;
  lq[tid] = q;
  __syncthreads();
  if (tid < 64) {
    s = ls[tid] + ls[tid + 64] + ls[tid + 128] + ls[tid + 192];
    q = lq[tid] + lq[tid + 64] + lq[tid + 128] + lq[tid + 192];
    atomicAdd(&stats[f], s);
    atomicAdd(&stats[64 + f], q);
  }
}

__global__ void bn_finalize(const float* __restrict__ stats, const float* __restrict__ g,
                            const float* __restrict__ be, float* __restrict__ ssc, int N) {
  int f = threadIdx.x;  // 64 threads
  float inv = 1.f / (float)N;
  float mu = stats[f] * inv;
  float var = stats[64 + f] * inv - mu * mu;
  float rstd = rsqrtf(var + 1e-5f);
  float sc = rstd * g[f];
  ssc[f] = sc;
  ssc[64 + f] = be[f] - mu * sc;
}

// ---------------- fused: nemb = elu(bn(pre3)); pool partial sums via per-wave run ----------------
__global__ void emb_pool_k(const float* __restrict__ pre, const float* __restrict__ ssc,
                           const int* __restrict__ batch, float* __restrict__ nemb,
                           float* __restrict__ pool, int N, int per) {
  int lane = threadIdx.x & 63, wid = threadIdx.x >> 6;
  int gw = blockIdx.x * 4 + wid;
  int n0 = gw * per;
  int n1 = n0 + per; if (n1 > N) n1 = N;
  if (n0 >= n1) return;
  float sc = ssc[lane], sh = ssc[64 + lane];
  float acc = 0.f;
  int cg = batch[n0];
  for (int n = n0; n < n1; n++) {
    int g = batch[n];
    if (g != cg) { atomicAdd(&pool[cg * 64 + lane], acc); acc = 0.f; cg = g; }
    float v = pre[(long long)n * 64 + lane] * sc + sh;
    v = v > 0.f ? v : (__expf(v) - 1.f);
    nemb[(long long)n * 64 + lane] = v;
    acc += v;
  }
  atomicAdd(&pool[cg * 64 + lane], acc);
}

// ---------------- classifier + embedding head, one block per graph ----------------
__global__ void head_k(const float* __restrict__ pool, const int* __restrict__ batch,
                       const float* __restrict__ Wc1, const float* __restrict__ bc1,
                       const float* __restrict__ Wc2, const float* __restrict__ bc2,
                       const float* __restrict__ We, const float* __restrict__ bee,
                       float* __restrict__ logits, float* __restrict__ emb, int N) {
  int g = blockIdx.x, lane = threadIdx.x;  // 64 threads
  __shared__ float pr[64], hid[32];
  __shared__ int bnds[2];
  if (lane < 2) {
    int target = g + lane;  // lower_bound(batch, target)
    int lo = 0, hi = N;
    while (lo < hi) {
      int mid = (lo + hi) >> 1;
      if (batch[mid] < target) lo = mid + 1; else hi = mid;
    }
    bnds[lane] = lo;
  }
  __syncthreads();
  float cnt = (float)(bnds[1] - bnds[0]);
  pr[lane] = pool[g * 64 + lane] / fmaxf(cnt, 1.f);
  __syncthreads();
  if (lane < 32) {
    float a = bc1[lane];
    for (int k = 0; k < 64; k++) a += pr[k] * Wc1[k * 32 + lane];
    hid[lane] = fmaxf(a, 0.f);
  }
  float e = bee[lane];
  for (int k = 0; k < 64; k++) e += pr[k] * We[k * 64 + lane];
  emb[g * 64 + lane] = e;
  __syncthreads();
  if (lane < 2) {
    float l = bc2[lane];
    for (int k = 0; k < 32; k++) l += hid[k] * Wc2[k * 2 + lane];
    logits[g * 2 + lane] = l;
  }
}

extern "C" void kernel_launch(void* const* d_in, const int* in_sizes, int n_in,
                              void* d_out, int out_size, void* d_ws, size_t ws_size,
                              hipStream_t stream) {
  const float* x    = (const float*)d_in[0];
  const int*   ei   = (const int*)d_in[1];
  const int*   batch= (const int*)d_in[2];
  const float* W1   = (const float*)d_in[3];
  const float* as1  = (const float*)d_in[4];
  const float* ad1  = (const float*)d_in[5];
  const float* b1   = (const float*)d_in[6];
  const float* g1   = (const float*)d_in[7];
  const float* be1  = (const float*)d_in[8];
  const float* W2   = (const float*)d_in[9];
  const float* as2  = (const float*)d_in[10];
  const float* ad2  = (const float*)d_in[11];
  const float* b2   = (const float*)d_in[12];
  const float* g2   = (const float*)d_in[13];
  const float* be2  = (const float*)d_in[14];
  const float* W3   = (const float*)d_in[15];
  const float* as3  = (const float*)d_in[16];
  const float* ad3  = (const float*)d_in[17];
  const float* b3   = (const float*)d_in[18];
  const float* g3   = (const float*)d_in[19];
  const float* be3  = (const float*)d_in[20];
  const float* Wc1  = (const float*)d_in[21];
  const float* bc1  = (const float*)d_in[22];
  const float* Wc2  = (const float*)d_in[23];
  const float* bc2  = (const float*)d_in[24];
  const float* We   = (const float*)d_in[25];
  const float* bee  = (const float*)d_in[26];

  int N = in_sizes[0] / 12;
  int E = in_sizes[1] / 2;
  const int* srcv = ei;
  const int* dstv = ei + E;

  char* p = (char*)d_ws;
  auto carve = [&](size_t bytes) -> char* {
    char* r = p;
    p += (bytes + 255) & ~(size_t)255;
    return r;
  };
  int* counts  = (int*)carve((size_t)N * 4);
  int* cursor  = (int*)carve((size_t)N * 4);
  int* offs    = (int*)carve((size_t)(N + 1) * 4);
  int* bsums   = (int*)carve(4096 * 4);
  int* csr     = (int*)carve((size_t)E * 4);
  __hip_bfloat16* h  = (__hip_bfloat16*)carve((size_t)N * 64 * 2);
  __hip_bfloat16* wt2 = (__hip_bfloat16*)carve(64 * 64 * 2);
  __hip_bfloat16* wt3 = (__hip_bfloat16*)carve(64 * 64 * 2);
  float* als   = (float*)carve((size_t)N * 4 * 4);
  float* ald   = (float*)carve((size_t)N * 4 * 4);
  float* preA  = (float*)carve((size_t)(N + 64) * 64 * 4);  // +64 pad rows for MFMA tiles
  float* preB  = (float*)carve((size_t)(N + 64) * 64 * 4);
  float* statsAll = (float*)carve(3 * 128 * 4);
  float* sscAll   = (float*)carve(3 * 128 * 4);
  float* poolbuf  = (float*)carve(64 * 64 * 4);

  hipMemsetAsync(counts, 0, (size_t)N * 4, stream);
  hipMemsetAsync(statsAll, 0, 3 * 128 * 4, stream);
  hipMemsetAsync(poolbuf, 0, 64 * 64 * 4, stream);
  hipMemsetAsync(preA + (size_t)N * 64, 0, 64 * 64 * 4, stream);
  hipMemsetAsync(preB + (size_t)N * 64, 0, 64 * 64 * 4, stream);

  int nbE = (E + THREADS - 1) / THREADS;
  int nbN = (N + THREADS - 1) / THREADS;
  int RS = (N + 7) / 8;  // dst-range size per XCD residue class
  wprep_k<<<2, THREADS, 0, stream>>>(W2, W3, wt2, wt3);
  hist_k<<<nbE, THREADS, 0, stream>>>(dstv, counts, E);
  scan1_k<<<nbN, THREADS, 0, stream>>>(counts, offs, bsums, N);
  scan2_k<<<1, 1024, 0, stream>>>(bsums, nbN);
  scan3_k<<<nbN, THREADS, 0, stream>>>(offs, cursor, bsums, N, E);
  scatter8_k<<<nbE * 8, THREADS, 0, stream>>>(srcv, dstv, cursor, csr, E, RS);

  int nbNode = (N + 3) / 4;
  int nbT = (N + 63) / 64;

  // ---- layer 1 (K=12, H=4, scalar) ----
  gat_transform<12><<<nbNode, THREADS, 0, stream>>>(x, W1, as1, ad1, h, als, ald, N, 4);
  gat_gather4<<<nbNode, THREADS, 0, stream>>>(h, als, ald, offs, csr, b1, preA, N);
  bn_stats<<<1024, THREADS, 0, stream>>>(preA, statsAll + 0, N);
  bn_finalize<<<1, 64, 0, stream>>>(statsAll + 0, g1, be1, sscAll + 0, N);
  // ---- layer 2 (K=64, H=4, MFMA, fused BN+ELU) ----
  transform_mfma<4><<<nbT, THREADS, 0, stream>>>(preA, sscAll + 0, wt2, as2, ad2, h, als, ald, N);
  gat_gather4<<<nbNode, THREADS, 0, stream>>>(h, als, ald, offs, csr, b2, preB, N);
  bn_stats<<<1024, THREADS, 0, stream>>>(preB, statsAll + 128, N);
  bn_finalize<<<1, 64, 0, stream>>>(statsAll + 128, g2, be2, sscAll + 128, N);
  // ---- layer 3 (K=64, H=1, MFMA, fused BN+ELU) ----
  transform_mfma<1><<<nbT, THREADS, 0, stream>>>(preB, sscAll + 128, wt3, as3, ad3, h, als, ald, N);
  gat_gather1<<<nbNode, THREADS, 0, stream>>>(h, als, ald, offs, csr, b3, preA, N);
  bn_stats<<<1024, THREADS, 0, stream>>>(preA, statsAll + 256, N);
  bn_finalize<<<1, 64, 0, stream>>>(statsAll + 256, g3, be3, sscAll + 256, N);

  float* outF   = (float*)d_out;
  float* logits = outF;
  float* emb    = outF + 64 * 2;
  float* nemb   = outF + 64 * 2 + 64 * 64;

  const int PER = 16;
  int nWaves = (N + PER - 1) / PER;
  int nbPool = (nWaves + 3) / 4;
  emb_pool_k<<<nbPool, THREADS, 0, stream>>>(preA, sscAll + 256, batch, nemb, poolbuf, N, PER);
  head_k<<<64, 64, 0, stream>>>(poolbuf, batch, Wc1, bc1, Wc2, bc2, We, bee, logits, emb, N);
}